// Round 15
// baseline (930.076 us; speedup 1.0000x reference)
//
#include <hip/hip_runtime.h>
#include <hip/hip_bf16.h>

#define NN 10000
#define NE 320000
#define HD 128
#define NL 6
#define EPSV 1e-5f

typedef _Float16 half8  __attribute__((ext_vector_type(8)));
typedef _Float16 half4v __attribute__((ext_vector_type(4)));
typedef float    f32x4  __attribute__((ext_vector_type(4)));

__device__ __forceinline__ float relu_(float x){ return fmaxf(x, 0.0f); }

// ---------------- degree / scan / place (CSR build) ----------------

__global__ void k_degree(const int* __restrict__ dst, int* __restrict__ counts){
  int e = blockIdx.x*256 + threadIdx.x;
  if (e < NE) atomicAdd(&counts[dst[e]], 1);
}

__global__ void k_scan(const int* __restrict__ counts, int* __restrict__ offs, float* __restrict__ invc){
  __shared__ int lds[1024];
  __shared__ int base_s;
  int tid = threadIdx.x;
  if (tid==0) base_s = 0;
  __syncthreads();
  for (int start=0; start<NN; start+=1024){
    int i = start+tid;
    int vv = (i<NN)? counts[i] : 0;
    lds[tid]=vv; __syncthreads();
    for (int off=1; off<1024; off<<=1){
      int t = (tid>=off)? lds[tid-off] : 0;
      __syncthreads();
      lds[tid] += t;
      __syncthreads();
    }
    int incl = lds[tid];
    if (i<NN){
      offs[i] = base_s + incl - vv;
      invc[i] = 1.0f / fmaxf((float)vv, 1.0f);
    }
    __syncthreads();
    if (tid==1023) base_s += lds[1023];
    __syncthreads();
  }
  if (tid==0) offs[NN] = base_s;
}

__global__ void k_place(const int* __restrict__ src, const int* __restrict__ dst,
                        const int* __restrict__ offs, int* __restrict__ cursor, int* __restrict__ csr){
  int e = blockIdx.x*256 + threadIdx.x;
  if (e < NE){
    int d = dst[e];
    int p = atomicAdd(&cursor[d], 1);
    csr[offs[d]+p] = src[e];
  }
}

// ---------------- fold gf into first-layer biases + init mu/rstd ----------------

__global__ void k_biasfold(const float* __restrict__ dom, const float* __restrict__ tt,
                           const float* __restrict__ xg, const float* __restrict__ domn,
                           const float* __restrict__ tn,
                           const float* __restrict__ embW1, const float* __restrict__ embB1,
                           const float* __restrict__ msgW1, const float* __restrict__ msgB1,
                           const float* __restrict__ updW1, const float* __restrict__ updB1,
                           float* __restrict__ b1eff, float* __restrict__ mu, float* __restrict__ rstd){
  float gf[12];
  gf[0]=dom[0]; gf[1]=dom[1]; gf[2]=dom[2]; gf[3]=tt[0];
  gf[4]=xg[0]; gf[5]=xg[1]; gf[6]=xg[2]; gf[7]=xg[3];
  gf[8]=domn[0]; gf[9]=domn[1]; gf[10]=domn[2]; gf[11]=tn[0];
  int b = blockIdx.x, t = threadIdx.x;
  if (b==0){
    float s = embB1[t];
    #pragma unroll
    for (int k=0;k<12;++k) s += gf[k]*embW1[(7+k)*HD + t];
    b1eff[t] = s;
  } else if (b<=6){
    int l=b-1;
    float s = msgB1[l*HD+t];
    #pragma unroll
    for (int k=0;k<12;++k) s += gf[k]*msgW1[((size_t)l*157 + 145+k)*HD + t];
    b1eff[(1+l)*HD + t] = s;
  } else if (b<=12){
    int l=b-7;
    float s = updB1[l*HD+t];
    #pragma unroll
    for (int k=0;k<12;++k) s += gf[k]*updW1[((size_t)l*268 + 256+k)*HD + t];
    b1eff[(7+l)*HD + t] = s;
  } else {
    mu[t] = 0.f;
    rstd[t] = 1.f;
  }
}

// ---------------- embedding via fp16-split MFMA (k_upd template) ----------------

__global__ __launch_bounds__(512,1) void k_embed(
    const float* __restrict__ r, const float* __restrict__ v,
    const float* __restrict__ W1, const float* __restrict__ b1e,
    const float* __restrict__ W2, const float* __restrict__ b2,
    float* __restrict__ hb){
  __shared__ alignas(16) _Float16 Ahi[16*136];
  __shared__ alignas(16) _Float16 Alo[16*136];
  int tid = threadIdx.x;
  int n0 = blockIdx.x*16;
  if (tid < 256){
    int node = tid>>4, chunk = tid&15;
    int n = n0 + node;
    int f = chunk*8;
    float in7[7];
    in7[0]=r[n];
    #pragma unroll
    for (int k=0;k<6;++k) in7[1+k]=v[n*6+k];
    half8 ah, al;
    #pragma unroll
    for (int j=0;j<8;++j){
      float z = b1e[f+j];
      #pragma unroll
      for (int k=0;k<7;++k) z += in7[k]*W1[k*HD + f+j];
      float a = fmaxf(z, 0.f);
      _Float16 h = (_Float16)a;
      ah[j] = h; al[j] = (_Float16)(a - (float)h);
    }
    *(half8*)&Ahi[node*136 + f] = ah;
    *(half8*)&Alo[node*136 + f] = al;
  }
  int wid = tid>>6, lane = tid&63, g = lane>>4, c = lane&15;
  int col = 16*wid + c;
  half8 bh[4], bl[4];
  #pragma unroll
  for (int ks=0; ks<4; ++ks){
    half8 fh, fl;
    #pragma unroll
    for (int j=0;j<8;++j){
      float w = W2[(size_t)(ks*32 + g*8 + j)*HD + col];
      _Float16 h = (_Float16)w;
      fh[j]=h; fl[j]=(_Float16)(w - (float)h);
    }
    bh[ks]=fh; bl[ks]=fl;
  }
  float b2c = b2[col];
  f32x4 zero4 = {0.f,0.f,0.f,0.f};
  __syncthreads();
  f32x4 d = zero4;
  #pragma unroll
  for (int ks=0; ks<4; ++ks){
    half8 ah = *(const half8*)&Ahi[c*136 + ks*32 + g*8];
    half8 al = *(const half8*)&Alo[c*136 + ks*32 + g*8];
    d = __builtin_amdgcn_mfma_f32_16x16x32_f16(ah, bh[ks], d, 0,0,0);
    d = __builtin_amdgcn_mfma_f32_16x16x32_f16(al, bh[ks], d, 0,0,0);
    d = __builtin_amdgcn_mfma_f32_16x16x32_f16(ah, bl[ks], d, 0,0,0);
  }
  #pragma unroll
  for (int jj=0;jj<4;++jj){
    int n = n0 + g*4 + jj;
    hb[(size_t)n*HD + col] = fmaxf(d[jj] + b2c, 0.f);
  }
}

// ---------------- P/Q via fp16-split MFMA (k_upd template) ----------------

__global__ __launch_bounds__(512,1) void k_hW(
    const float* __restrict__ hb, const float* __restrict__ mu, const float* __restrict__ rstd,
    const float* __restrict__ v, const float* __restrict__ r,
    const float* __restrict__ W, const float* __restrict__ b1e,
    float* __restrict__ P, float* __restrict__ Q){
  __shared__ alignas(16) _Float16 Xhi[16*136];
  __shared__ alignas(16) _Float16 Xlo[16*136];
  int tid = threadIdx.x;
  int n0 = blockIdx.x*16;
  if (tid < 256){
    int node = tid>>4, chunk = tid&15;
    int n = n0 + node;
    int f = chunk*8;
    half8 xh, xl;
    #pragma unroll
    for (int j=0;j<8;++j){
      float x = (hb[(size_t)n*HD + f+j] - mu[f+j]) * rstd[f+j];
      _Float16 h = (_Float16)x;
      xh[j] = h; xl[j] = (_Float16)(x - (float)h);
    }
    *(half8*)&Xhi[node*136 + f] = xh;
    *(half8*)&Xlo[node*136 + f] = xl;
  }
  int wid = tid>>6, lane = tid&63, g = lane>>4, c = lane&15;
  int col = 16*wid + c;
  half8 bh[4], bl[4];
  #pragma unroll
  for (int ks=0; ks<4; ++ks){
    half8 fh, fl;
    #pragma unroll
    for (int j=0;j<8;++j){
      float w = W[(size_t)(ks*32 + g*8 + j)*HD + col];
      _Float16 h = (_Float16)w;
      fh[j]=h; fl[j]=(_Float16)(w - (float)h);
    }
    bh[ks]=fh; bl[ks]=fl;
  }
  float wvi[6], wvj[6];
  #pragma unroll
  for (int x=0;x<6;++x){
    wvi[x]=W[(size_t)(128+x)*HD+col];
    wvj[x]=W[(size_t)(134+x)*HD+col];
  }
  float wri=W[(size_t)140*HD+col], wrj=W[(size_t)141*HD+col];
  float b1c=b1e[col];
  f32x4 zero4 = {0.f,0.f,0.f,0.f};
  __syncthreads();
  f32x4 d = zero4;
  #pragma unroll
  for (int ks=0; ks<4; ++ks){
    half8 ah = *(const half8*)&Xhi[c*136 + ks*32 + g*8];
    half8 al = *(const half8*)&Xlo[c*136 + ks*32 + g*8];
    d = __builtin_amdgcn_mfma_f32_16x16x32_f16(ah, bh[ks], d, 0,0,0);
    d = __builtin_amdgcn_mfma_f32_16x16x32_f16(al, bh[ks], d, 0,0,0);
    d = __builtin_amdgcn_mfma_f32_16x16x32_f16(ah, bl[ks], d, 0,0,0);
  }
  #pragma unroll
  for (int jj=0;jj<4;++jj){
    int n = n0 + g*4 + jj;
    float m = d[jj];
    float p = m + b1c, q = -m;
    #pragma unroll
    for (int x=0;x<6;++x){
      float vx = v[n*6+x];
      p += vx*wvi[x]; q += vx*wvj[x];
    }
    float rn = r[n];
    p += rn*wri; q += rn*wrj;
    P[(size_t)n*HD+col]=p;
    Q[(size_t)n*HD+col]=q;
  }
}

// ---------------- edge MLP via fp16-split MFMA, 32-edge tiles ----------------
// 5000 blocks x 2 dst nodes. Single a1 buffer (32 rows), TWO barriers per
// 32-edge tile-pair (proven write->barrier->read->barrier protocol, 2x phase size).

__global__ __launch_bounds__(256,2) void k_edge(
    const float* __restrict__ P, const float* __restrict__ Q,
    const float* __restrict__ pos, const float* __restrict__ dom,
    const int* __restrict__ offs, const int* __restrict__ csr,
    const float* __restrict__ Wpd, const float* __restrict__ W2, const float* __restrict__ b2,
    const float* __restrict__ invc, float* __restrict__ agg,
    float* __restrict__ zsum, float* __restrict__ zsumsq){
  __shared__ alignas(16) _Float16 w1pd[128*40];     // [f][k] stride 40
  __shared__ alignas(16) _Float16 a1hi[32*136];     // [edge 0..31][f]
  __shared__ alignas(16) _Float16 a1lo[32*136];
  int tid = threadIdx.x;
  if (blockIdx.x==0 && tid<HD){ zsum[tid]=0.f; zsumsq[tid]=0.f; }
  if (tid < 128){
    int f = tid;
    #pragma unroll
    for (int k=0;k<32;++k) w1pd[f*40+k] = (_Float16)0.f;
    #pragma unroll
    for (int x=0;x<3;++x){
      float w = Wpd[x*HD + f];
      _Float16 h = (_Float16)w;
      w1pd[f*40 + x]     = h;
      w1pd[f*40 + 3 + x] = h;
      w1pd[f*40 + 6 + x] = (_Float16)(w - (float)h);
    }
  }
  int wid = tid>>6, lane = tid&63, g = lane>>4, c = lane&15;
  int t0 = 2*wid, t1 = 2*wid+1;
  half8 w2h[4][2], w2l[4][2];
  #pragma unroll
  for (int ks=0; ks<4; ++ks){
    #pragma unroll
    for (int tt=0; tt<2; ++tt){
      int col = 16*(2*wid+tt) + c;
      half8 fh, fl;
      #pragma unroll
      for (int j=0;j<8;++j){
        float w = W2[(ks*32 + g*8 + j)*HD + col];
        _Float16 h = (_Float16)w;
        fh[j] = h;
        fl[j] = (_Float16)(w - (float)h);
      }
      w2h[ks][tt] = fh;
      w2l[ks][tt] = fl;
    }
  }
  float b2v0 = b2[16*t0 + c], b2v1 = b2[16*t1 + c];
  float dm0=dom[0], dm1=dom[1], dm2=dom[2];
  f32x4 zero4 = {0.f,0.f,0.f,0.f};
  half8 w1f0 = *(const half8*)&w1pd[(16*t0 + c)*40 + g*8];  // safe: written by tid<128 pre-read?  -- must come after barrier
  __syncthreads();
  w1f0 = *(const half8*)&w1pd[(16*t0 + c)*40 + g*8];
  half8 w1f1 = *(const half8*)&w1pd[(16*t1 + c)*40 + g*8];
  int n0 = blockIdx.x*2;
  for (int n = n0; n < n0+2; ++n){
    f32x4 pv0 = *(const f32x4*)(P + (size_t)n*HD + 16*t0 + 4*g);
    f32x4 pv1 = *(const f32x4*)(P + (size_t)n*HD + 16*t1 + 4*g);
    float pn0=pos[n*3+0], pn1=pos[n*3+1], pn2=pos[n*3+2];
    float acc0=0.f, acc1=0.f;
    int ib=offs[n], ie=offs[n+1];
    for (int base=ib; base<ie; base+=32){
      int nb = ie - base; if (nb>32) nb = 32;
      // ---- group 0: edges base + c ----
      {
        int sA = csr[base + ((c<nb)? c : nb-1)];
        float q0=pos[sA*3+0], q1=pos[sA*3+1], q2=pos[sA*3+2];
        float pd0,pd1,pd2;
        { float diff,sh,ds;
          diff=pn0-q0; sh=(pn0<q0)?-dm0:dm0; ds=diff-sh; pd0=(fabsf(diff)<fabsf(ds))?diff:ds;
          diff=pn1-q1; sh=(pn1<q1)?-dm1:dm1; ds=diff-sh; pd1=(fabsf(diff)<fabsf(ds))?diff:ds;
          diff=pn2-q2; sh=(pn2<q2)?-dm2:dm2; ds=diff-sh; pd2=(fabsf(diff)<fabsf(ds))?diff:ds;
        }
        _Float16 p0h=(_Float16)pd0, p1h=(_Float16)pd1, p2h=(_Float16)pd2;
        _Float16 p0l=(_Float16)(pd0-(float)p0h), p1l=(_Float16)(pd1-(float)p1h), p2l=(_Float16)(pd2-(float)p2h);
        half8 pdf;
        #pragma unroll
        for (int j=0;j<8;++j) pdf[j]=(_Float16)0.f;
        if (g==0){ pdf[0]=p0h; pdf[1]=p1h; pdf[2]=p2h; pdf[3]=p0l; pdf[4]=p1l; pdf[5]=p2l; pdf[6]=p0h; pdf[7]=p1h; }
        else if (g==1){ pdf[0]=p2h; }
        f32x4 d0 = __builtin_amdgcn_mfma_f32_16x16x32_f16(w1f0, pdf, zero4, 0,0,0);
        f32x4 d1 = __builtin_amdgcn_mfma_f32_16x16x32_f16(w1f1, pdf, zero4, 0,0,0);
        const float* Qs = Q + (size_t)sA*HD;
        f32x4 qv0 = *(const f32x4*)(Qs + 16*t0 + 4*g);
        f32x4 qv1 = *(const f32x4*)(Qs + 16*t1 + 4*g);
        half4v h0, l0, h1, l1;
        #pragma unroll
        for (int j=0;j<4;++j){
          float a = fmaxf(d0[j] + pv0[j] + qv0[j], 0.f);
          _Float16 hh = (_Float16)a;
          h0[j] = hh; l0[j] = (_Float16)(a - (float)hh);
          float b = fmaxf(d1[j] + pv1[j] + qv1[j], 0.f);
          _Float16 hb2 = (_Float16)b;
          h1[j] = hb2; l1[j] = (_Float16)(b - (float)hb2);
        }
        *(half4v*)&a1hi[c*136 + 16*t0 + 4*g] = h0;
        *(half4v*)&a1lo[c*136 + 16*t0 + 4*g] = l0;
        *(half4v*)&a1hi[c*136 + 16*t1 + 4*g] = h1;
        *(half4v*)&a1lo[c*136 + 16*t1 + 4*g] = l1;
      }
      // ---- group 1: edges base + 16 + c ----
      {
        int sA = csr[base + ((16+c<nb)? 16+c : nb-1)];
        float q0=pos[sA*3+0], q1=pos[sA*3+1], q2=pos[sA*3+2];
        float pd0,pd1,pd2;
        { float diff,sh,ds;
          diff=pn0-q0; sh=(pn0<q0)?-dm0:dm0; ds=diff-sh; pd0=(fabsf(diff)<fabsf(ds))?diff:ds;
          diff=pn1-q1; sh=(pn1<q1)?-dm1:dm1; ds=diff-sh; pd1=(fabsf(diff)<fabsf(ds))?diff:ds;
          diff=pn2-q2; sh=(pn2<q2)?-dm2:dm2; ds=diff-sh; pd2=(fabsf(diff)<fabsf(ds))?diff:ds;
        }
        _Float16 p0h=(_Float16)pd0, p1h=(_Float16)pd1, p2h=(_Float16)pd2;
        _Float16 p0l=(_Float16)(pd0-(float)p0h), p1l=(_Float16)(pd1-(float)p1h), p2l=(_Float16)(pd2-(float)p2h);
        half8 pdf;
        #pragma unroll
        for (int j=0;j<8;++j) pdf[j]=(_Float16)0.f;
        if (g==0){ pdf[0]=p0h; pdf[1]=p1h; pdf[2]=p2h; pdf[3]=p0l; pdf[4]=p1l; pdf[5]=p2l; pdf[6]=p0h; pdf[7]=p1h; }
        else if (g==1){ pdf[0]=p2h; }
        f32x4 d0 = __builtin_amdgcn_mfma_f32_16x16x32_f16(w1f0, pdf, zero4, 0,0,0);
        f32x4 d1 = __builtin_amdgcn_mfma_f32_16x16x32_f16(w1f1, pdf, zero4, 0,0,0);
        const float* Qs = Q + (size_t)sA*HD;
        f32x4 qv0 = *(const f32x4*)(Qs + 16*t0 + 4*g);
        f32x4 qv1 = *(const f32x4*)(Qs + 16*t1 + 4*g);
        half4v h0, l0, h1, l1;
        #pragma unroll
        for (int j=0;j<4;++j){
          float a = fmaxf(d0[j] + pv0[j] + qv0[j], 0.f);
          _Float16 hh = (_Float16)a;
          h0[j] = hh; l0[j] = (_Float16)(a - (float)hh);
          float b = fmaxf(d1[j] + pv1[j] + qv1[j], 0.f);
          _Float16 hb2 = (_Float16)b;
          h1[j] = hb2; l1[j] = (_Float16)(b - (float)hb2);
        }
        *(half4v*)&a1hi[(16+c)*136 + 16*t0 + 4*g] = h0;
        *(half4v*)&a1lo[(16+c)*136 + 16*t0 + 4*g] = l0;
        *(half4v*)&a1hi[(16+c)*136 + 16*t1 + 4*g] = h1;
        *(half4v*)&a1lo[(16+c)*136 + 16*t1 + 4*g] = l1;
      }
      __syncthreads();
      // ---- GEMM2 over both row-tiles: m[R][tt], rows = R*16 + 4g+j ----
      #pragma unroll
      for (int R=0; R<2; ++R){
        f32x4 m0 = zero4, m1 = zero4;
        #pragma unroll
        for (int ks=0; ks<4; ++ks){
          half8 ah = *(const half8*)&a1hi[(R*16+c)*136 + ks*32 + g*8];
          half8 al = *(const half8*)&a1lo[(R*16+c)*136 + ks*32 + g*8];
          m0 = __builtin_amdgcn_mfma_f32_16x16x32_f16(ah, w2h[ks][0], m0, 0,0,0);
          m0 = __builtin_amdgcn_mfma_f32_16x16x32_f16(al, w2h[ks][0], m0, 0,0,0);
          m0 = __builtin_amdgcn_mfma_f32_16x16x32_f16(ah, w2l[ks][0], m0, 0,0,0);
          m1 = __builtin_amdgcn_mfma_f32_16x16x32_f16(ah, w2h[ks][1], m1, 0,0,0);
          m1 = __builtin_amdgcn_mfma_f32_16x16x32_f16(al, w2h[ks][1], m1, 0,0,0);
          m1 = __builtin_amdgcn_mfma_f32_16x16x32_f16(ah, w2l[ks][1], m1, 0,0,0);
        }
        int e0 = R*16 + 4*g;
        if (nb >= e0+4){
          acc0 += fmaxf(m0[0]+b2v0,0.f)+fmaxf(m0[1]+b2v0,0.f)+fmaxf(m0[2]+b2v0,0.f)+fmaxf(m0[3]+b2v0,0.f);
          acc1 += fmaxf(m1[0]+b2v1,0.f)+fmaxf(m1[1]+b2v1,0.f)+fmaxf(m1[2]+b2v1,0.f)+fmaxf(m1[3]+b2v1,0.f);
        } else {
          #pragma unroll
          for (int j=0;j<4;++j){
            if (e0+j < nb){
              acc0 += fmaxf(m0[j]+b2v0, 0.f);
              acc1 += fmaxf(m1[j]+b2v1, 0.f);
            }
          }
        }
      }
      __syncthreads();
    }
    acc0 += __shfl_xor(acc0, 16); acc0 += __shfl_xor(acc0, 32);
    acc1 += __shfl_xor(acc1, 16); acc1 += __shfl_xor(acc1, 32);
    if (g==0){
      float ic = invc[n];
      agg[n*HD + 16*t0 + c] = acc0*ic;
      agg[n*HD + 16*t1 + c] = acc1*ic;
    }
  }
}

// ---------------- update MLP via fp16-split MFMA ----------------

__global__ __launch_bounds__(512,1) void k_upd(
    float* __restrict__ hb, const float* __restrict__ mu, const float* __restrict__ rstd,
    const float* __restrict__ agg,
    const float* __restrict__ U1, const float* __restrict__ b1e,
    const float* __restrict__ U2, const float* __restrict__ bs2,
    float* __restrict__ sum, float* __restrict__ sumsq){
  __shared__ alignas(16) _Float16 Xhi[16*264];
  __shared__ alignas(16) _Float16 Xlo[16*264];
  __shared__ alignas(16) _Float16 Ahi[16*136];
  __shared__ alignas(16) _Float16 Alo[16*136];
  int tid = threadIdx.x;
  int n0 = blockIdx.x*16;
  {
    int node = tid>>5, chunk = tid&31;
    int n = n0 + node;
    int f = chunk*8;
    half8 xh, xl;
    if (f < 128){
      #pragma unroll
      for (int j=0;j<8;++j){
        float x = (hb[(size_t)n*HD + f+j] - mu[f+j]) * rstd[f+j];
        _Float16 h = (_Float16)x;
        xh[j] = h; xl[j] = (_Float16)(x - (float)h);
      }
    } else {
      #pragma unroll
      for (int j=0;j<8;++j){
        float x = agg[(size_t)n*HD + (f-128)+j];
        _Float16 h = (_Float16)x;
        xh[j] = h; xl[j] = (_Float16)(x - (float)h);
      }
    }
    *(half8*)&Xhi[node*264 + f] = xh;
    *(half8*)&Xlo[node*264 + f] = xl;
  }
  int wid = tid>>6, lane = tid&63, g = lane>>4, c = lane&15;
  int col = 16*wid + c;
  half8 b1h[8], b1l[8], b2h[4], b2l[4];
  #pragma unroll
  for (int ks=0; ks<8; ++ks){
    half8 fh, fl;
    #pragma unroll
    for (int j=0;j<8;++j){
      float w = U1[(size_t)(ks*32 + g*8 + j)*HD + col];
      _Float16 h = (_Float16)w;
      fh[j]=h; fl[j]=(_Float16)(w - (float)h);
    }
    b1h[ks]=fh; b1l[ks]=fl;
  }
  #pragma unroll
  for (int ks=0; ks<4; ++ks){
    half8 fh, fl;
    #pragma unroll
    for (int j=0;j<8;++j){
      float w = U2[(size_t)(ks*32 + g*8 + j)*HD + col];
      _Float16 h = (_Float16)w;
      fh[j]=h; fl[j]=(_Float16)(w - (float)h);
    }
    b2h[ks]=fh; b2l[ks]=fl;
  }
  f32x4 zero4 = {0.f,0.f,0.f,0.f};
  __syncthreads();
  f32x4 d = zero4;
  #pragma unroll
  for (int ks=0; ks<8; ++ks){
    half8 ah = *(const half8*)&Xhi[c*264 + ks*32 + g*8];
    half8 al = *(const half8*)&Xlo[c*264 + ks*32 + g*8];
    d = __builtin_amdgcn_mfma_f32_16x16x32_f16(ah, b1h[ks], d, 0,0,0);
    d = __builtin_amdgcn_mfma_f32_16x16x32_f16(al, b1h[ks], d, 0,0,0);
    d = __builtin_amdgcn_mfma_f32_16x16x32_f16(ah, b1l[ks], d, 0,0,0);
  }
  {
    float bb = b1e[col];
    #pragma unroll
    for (int jj=0;jj<4;++jj){
      float a = fmaxf(d[jj] + bb, 0.f);
      _Float16 h = (_Float16)a;
      Ahi[(g*4+jj)*136 + col] = h;
      Alo[(g*4+jj)*136 + col] = (_Float16)(a - (float)h);
    }
  }
  __syncthreads();
  f32x4 u = zero4;
  #pragma unroll
  for (int ks=0; ks<4; ++ks){
    half8 ah = *(const half8*)&Ahi[c*136 + ks*32 + g*8];
    half8 al = *(const half8*)&Alo[c*136 + ks*32 + g*8];
    u = __builtin_amdgcn_mfma_f32_16x16x32_f16(ah, b2h[ks], u, 0,0,0);
    u = __builtin_amdgcn_mfma_f32_16x16x32_f16(al, b2h[ks], u, 0,0,0);
    u = __builtin_amdgcn_mfma_f32_16x16x32_f16(ah, b2l[ks], u, 0,0,0);
  }
  float bc = bs2[col];
  float mc = mu[col], rc = rstd[col];
  float s=0.f, q=0.f;
  #pragma unroll
  for (int jj=0;jj<4;++jj){
    int n = n0 + g*4 + jj;
    float hn = (hb[(size_t)n*HD + col] - mc)*rc;
    float b0 = hn + fmaxf(u[jj] + bc, 0.f);
    hb[(size_t)n*HD + col] = b0;
    s += b0; q += b0*b0;
  }
  s += __shfl_xor(s,16); s += __shfl_xor(s,32);
  q += __shfl_xor(q,16); q += __shfl_xor(q,32);
  if (g==0){
    atomicAdd(&sum[col], s);
    atomicAdd(&sumsq[col], q);
  }
}

__global__ void k_normfin(const float* __restrict__ sum, const float* __restrict__ sumsq,
                          float* __restrict__ mu, float* __restrict__ rstd){
  int t=threadIdx.x;
  float m = sum[t]*(1.0f/NN);
  float var = sumsq[t]*(1.0f/NN) - m*m;
  mu[t]=m;
  rstd[t]=rsqrtf(fmaxf(var,0.0f)+EPSV);
}

// ---------------- decoder via fp16-split MFMA (k_upd template) ----------------
// 625 blocks x 512 threads; 16 nodes/block. GEMM1 full; GEMM2 (K=128, 9 cols,
// zero-padded) + epilogue on wave 0 only.

__global__ __launch_bounds__(512,1) void k_out(
    const float* __restrict__ hb, const float* __restrict__ mu, const float* __restrict__ rstd,
    const float* __restrict__ pos, const float* __restrict__ v,
    const float* __restrict__ W1, const float* __restrict__ b1,
    const float* __restrict__ W2, const float* __restrict__ b2,
    const float* __restrict__ domn, float* __restrict__ out){
  __shared__ alignas(16) _Float16 Xhi[16*136];
  __shared__ alignas(16) _Float16 Xlo[16*136];
  __shared__ alignas(16) _Float16 Ahi[16*136];
  __shared__ alignas(16) _Float16 Alo[16*136];
  int tid = threadIdx.x;
  int n0 = blockIdx.x*16;
  if (tid < 256){
    int node = tid>>4, chunk = tid&15;
    int n = n0 + node;
    int f = chunk*8;
    half8 xh, xl;
    #pragma unroll
    for (int j=0;j<8;++j){
      float x = (hb[(size_t)n*HD + f+j] - mu[f+j]) * rstd[f+j];
      _Float16 h = (_Float16)x;
      xh[j] = h; xl[j] = (_Float16)(x - (float)h);
    }
    *(half8*)&Xhi[node*136 + f] = xh;
    *(half8*)&Xlo[node*136 + f] = xl;
  }
  int wid = tid>>6, lane = tid&63, g = lane>>4, c = lane&15;
  int col = 16*wid + c;
  half8 bh[4], bl[4];
  #pragma unroll
  for (int ks=0; ks<4; ++ks){
    half8 fh, fl;
    #pragma unroll
    for (int j=0;j<8;++j){
      float w = W1[(size_t)(ks*32 + g*8 + j)*HD + col];
      _Float16 h = (_Float16)w;
      fh[j]=h; fl[j]=(_Float16)(w - (float)h);
    }
    bh[ks]=fh; bl[ks]=fl;
  }
  // W2 (128x9) frags for wave 0's GEMM2, zero-padded cols 9..15
  half8 w9h[4], w9l[4];
  if (wid==0){
    #pragma unroll
    for (int ks=0; ks<4; ++ks){
      half8 fh, fl;
      #pragma unroll
      for (int j=0;j<8;++j){
        float w = (c<9)? W2[(size_t)(ks*32 + g*8 + j)*9 + c] : 0.f;
        _Float16 h = (_Float16)w;
        fh[j]=h; fl[j]=(_Float16)(w - (float)h);
      }
      w9h[ks]=fh; w9l[ks]=fl;
    }
  }
  float b1c = b1[col];
  f32x4 zero4 = {0.f,0.f,0.f,0.f};
  __syncthreads();
  f32x4 d = zero4;
  #pragma unroll
  for (int ks=0; ks<4; ++ks){
    half8 ah = *(const half8*)&Xhi[c*136 + ks*32 + g*8];
    half8 al = *(const half8*)&Xlo[c*136 + ks*32 + g*8];
    d = __builtin_amdgcn_mfma_f32_16x16x32_f16(ah, bh[ks], d, 0,0,0);
    d = __builtin_amdgcn_mfma_f32_16x16x32_f16(al, bh[ks], d, 0,0,0);
    d = __builtin_amdgcn_mfma_f32_16x16x32_f16(ah, bl[ks], d, 0,0,0);
  }
  #pragma unroll
  for (int jj=0;jj<4;++jj){
    float a = fmaxf(d[jj] + b1c, 0.f);
    _Float16 h = (_Float16)a;
    Ahi[(g*4+jj)*136 + col] = h;
    Alo[(g*4+jj)*136 + col] = (_Float16)(a - (float)h);
  }
  __syncthreads();
  if (wid==0){
    f32x4 u = zero4;
    #pragma unroll
    for (int ks=0; ks<4; ++ks){
      half8 ah = *(const half8*)&Ahi[c*136 + ks*32 + g*8];
      half8 al = *(const half8*)&Alo[c*136 + ks*32 + g*8];
      u = __builtin_amdgcn_mfma_f32_16x16x32_f16(ah, w9h[ks], u, 0,0,0);
      u = __builtin_amdgcn_mfma_f32_16x16x32_f16(al, w9h[ks], u, 0,0,0);
      u = __builtin_amdgcn_mfma_f32_16x16x32_f16(ah, w9l[ks], u, 0,0,0);
    }
    if (c < 9){
      float bc = b2[c];
      #pragma unroll
      for (int jj=0;jj<4;++jj){
        int n = n0 + g*4 + jj;
        float p = u[jj] + bc;
        if (c < 3){
          p += pos[n*3+c];
          float dd = domn[c];
          p = p - floorf(p/dd)*dd;
          out[n*3+c] = p;
        } else {
          p += v[n*6 + (c-3)];
          out[3*NN + n*6 + (c-3)] = p;
        }
      }
    }
  }
}

__global__ void k_macro(const float* __restrict__ sum, const float* __restrict__ mu, const float* __restrict__ rstd,
                        const float* __restrict__ W1, const float* __restrict__ b1,
                        const float* __restrict__ W2, const float* __restrict__ b2,
                        float* __restrict__ out){
  __shared__ float hm[HD];
  __shared__ float as[HD];
  int t=threadIdx.x;
  hm[t] = (sum[t]*(1.0f/NN) - mu[t])*rstd[t];
  __syncthreads();
  float z=b1[t];
  for (int k=0;k<HD;++k) z += hm[k]*W1[k*HD+t];
  as[t]=relu_(z);
  __syncthreads();
  if (t<3){
    float p=b2[t];
    for (int k=0;k<HD;++k) p += as[k]*W2[k*3+t];
    out[9*NN+t]=p;
  }
}

// ---------------- host launch ----------------

extern "C" void kernel_launch(void* const* d_in, const int* in_sizes, int n_in,
                              void* d_out, int out_size, void* d_ws, size_t ws_size,
                              hipStream_t stream) {
  const float* v    = (const float*)d_in[0];
  const float* pos  = (const float*)d_in[1];
  const float* r    = (const float*)d_in[2];
  const float* dom  = (const float*)d_in[3];
  const float* tt   = (const float*)d_in[4];
  const float* xg   = (const float*)d_in[5];
  const float* domn = (const float*)d_in[6];
  const float* tn   = (const float*)d_in[7];
  const int*   eidx = (const int*)d_in[8];
  const float* embW1 = (const float*)d_in[10];
  const float* embB1 = (const float*)d_in[11];
  const float* embW2 = (const float*)d_in[12];
  const float* embB2 = (const float*)d_in[13];
  const float* msgW1 = (const float*)d_in[14];
  const float* msgB1 = (const float*)d_in[15];
  const float* msgW2 = (const float*)d_in[16];
  const float* msgB2 = (const float*)d_in[17];
  const float* updW1 = (const float*)d_in[18];
  const float* updB1 = (const float*)d_in[19];
  const float* updW2 = (const float*)d_in[20];
  const float* updB2 = (const float*)d_in[21];
  const float* outW1 = (const float*)d_in[22];
  const float* outB1 = (const float*)d_in[23];
  const float* outW2 = (const float*)d_in[24];
  const float* outB2 = (const float*)d_in[25];
  const float* macW1 = (const float*)d_in[26];
  const float* macB1 = (const float*)d_in[27];
  const float* macW2 = (const float*)d_in[28];
  const float* macB2 = (const float*)d_in[29];
  float* out = (float*)d_out;
  float* ws  = (float*)d_ws;

  float* hb    = ws;
  float* P     = ws + 1280000;
  float* Q     = ws + 2560000;
  float* agg   = ws + 3840000;
  float* invc  = ws + 5120000;
  float* b1eff = ws + 5130000;   // 13*128
  float* sum   = ws + 5131664;
  float* sumsq = ws + 5131792;
  float* mu    = ws + 5131920;
  float* rstd  = ws + 5132048;
  int* counts  = (int*)(ws + 5132304);
  int* offs    = counts + NN;       // NN+1
  int* cursor  = offs + NN + 1;
  int* csr     = cursor + NN;       // NE

  const int* srcA = eidx;
  const int* dstA = eidx + NE;

  hipMemsetAsync(counts, 0, NN*sizeof(int), stream);
  hipMemsetAsync(cursor, 0, NN*sizeof(int), stream);

  k_degree<<<(NE+255)/256, 256, 0, stream>>>(dstA, counts);
  k_scan<<<1, 1024, 0, stream>>>(counts, offs, invc);
  k_place<<<(NE+255)/256, 256, 0, stream>>>(srcA, dstA, offs, cursor, csr);
  k_biasfold<<<14, 128, 0, stream>>>(dom, tt, xg, domn, tn, embW1, embB1, msgW1, msgB1, updW1, updB1,
                                     b1eff, mu, rstd);
  k_embed<<<625, 512, 0, stream>>>(r, v, embW1, b1eff, embW2, embB2, hb);

  for (int l=0; l<NL; ++l){
    k_hW<<<625,512,0,stream>>>(hb, mu, rstd, v, r, msgW1 + (size_t)l*157*HD, b1eff + (1+l)*HD, P, Q);
    k_edge<<<5000,256,0,stream>>>(P, Q, pos, dom, offs, csr,
        msgW1 + ((size_t)l*157+142)*HD,
        msgW2 + (size_t)l*HD*HD, msgB2 + l*HD, invc, agg, sum, sumsq);
    k_upd<<<625,512,0,stream>>>(hb, mu, rstd, agg,
        updW1 + (size_t)l*268*HD, b1eff + (7+l)*HD,
        updW2 + (size_t)l*HD*HD, updB2 + l*HD, sum, sumsq);
    k_normfin<<<1,128,0,stream>>>(sum, sumsq, mu, rstd);
  }

  k_out<<<625,512,0,stream>>>(hb, mu, rstd, pos, v, outW1, outB1, outW2, outB2, domn, out);
  k_macro<<<1,128,0,stream>>>(sum, mu, rstd, macW1, macB1, macW2, macB2, out);
}

// Round 16
// 833.971 us; speedup vs baseline: 1.1152x; 1.1152x over previous
//
#include <hip/hip_runtime.h>
#include <hip/hip_bf16.h>

#define NN 10000
#define NE 320000
#define HD 128
#define NL 6
#define EPSV 1e-5f

typedef _Float16 half8  __attribute__((ext_vector_type(8)));
typedef _Float16 half4v __attribute__((ext_vector_type(4)));
typedef float    f32x4  __attribute__((ext_vector_type(4)));

__device__ __forceinline__ float relu_(float x){ return fmaxf(x, 0.0f); }

// ---------------- degree / scan / place (CSR build) ----------------

__global__ void k_degree(const int* __restrict__ dst, int* __restrict__ counts){
  int e = blockIdx.x*256 + threadIdx.x;
  if (e < NE) atomicAdd(&counts[dst[e]], 1);
}

__global__ void k_scan(const int* __restrict__ counts, int* __restrict__ offs, float* __restrict__ invc){
  __shared__ int lds[1024];
  __shared__ int base_s;
  int tid = threadIdx.x;
  if (tid==0) base_s = 0;
  __syncthreads();
  for (int start=0; start<NN; start+=1024){
    int i = start+tid;
    int vv = (i<NN)? counts[i] : 0;
    lds[tid]=vv; __syncthreads();
    for (int off=1; off<1024; off<<=1){
      int t = (tid>=off)? lds[tid-off] : 0;
      __syncthreads();
      lds[tid] += t;
      __syncthreads();
    }
    int incl = lds[tid];
    if (i<NN){
      offs[i] = base_s + incl - vv;
      invc[i] = 1.0f / fmaxf((float)vv, 1.0f);
    }
    __syncthreads();
    if (tid==1023) base_s += lds[1023];
    __syncthreads();
  }
  if (tid==0) offs[NN] = base_s;
}

__global__ void k_place(const int* __restrict__ src, const int* __restrict__ dst,
                        const int* __restrict__ offs, int* __restrict__ cursor, int* __restrict__ csr){
  int e = blockIdx.x*256 + threadIdx.x;
  if (e < NE){
    int d = dst[e];
    int p = atomicAdd(&cursor[d], 1);
    csr[offs[d]+p] = src[e];
  }
}

// ---------------- fold gf into first-layer biases + init mu/rstd ----------------

__global__ void k_biasfold(const float* __restrict__ dom, const float* __restrict__ tt,
                           const float* __restrict__ xg, const float* __restrict__ domn,
                           const float* __restrict__ tn,
                           const float* __restrict__ embW1, const float* __restrict__ embB1,
                           const float* __restrict__ msgW1, const float* __restrict__ msgB1,
                           const float* __restrict__ updW1, const float* __restrict__ updB1,
                           float* __restrict__ b1eff, float* __restrict__ mu, float* __restrict__ rstd){
  float gf[12];
  gf[0]=dom[0]; gf[1]=dom[1]; gf[2]=dom[2]; gf[3]=tt[0];
  gf[4]=xg[0]; gf[5]=xg[1]; gf[6]=xg[2]; gf[7]=xg[3];
  gf[8]=domn[0]; gf[9]=domn[1]; gf[10]=domn[2]; gf[11]=tn[0];
  int b = blockIdx.x, t = threadIdx.x;
  if (b==0){
    float s = embB1[t];
    #pragma unroll
    for (int k=0;k<12;++k) s += gf[k]*embW1[(7+k)*HD + t];
    b1eff[t] = s;
  } else if (b<=6){
    int l=b-1;
    float s = msgB1[l*HD+t];
    #pragma unroll
    for (int k=0;k<12;++k) s += gf[k]*msgW1[((size_t)l*157 + 145+k)*HD + t];
    b1eff[(1+l)*HD + t] = s;
  } else if (b<=12){
    int l=b-7;
    float s = updB1[l*HD+t];
    #pragma unroll
    for (int k=0;k<12;++k) s += gf[k]*updW1[((size_t)l*268 + 256+k)*HD + t];
    b1eff[(7+l)*HD + t] = s;
  } else {
    mu[t] = 0.f;
    rstd[t] = 1.f;
  }
}

// ---------------- embedding via fp16-split MFMA (k_upd template) ----------------

__global__ __launch_bounds__(512,1) void k_embed(
    const float* __restrict__ r, const float* __restrict__ v,
    const float* __restrict__ W1, const float* __restrict__ b1e,
    const float* __restrict__ W2, const float* __restrict__ b2,
    float* __restrict__ hb){
  __shared__ alignas(16) _Float16 Ahi[16*136];
  __shared__ alignas(16) _Float16 Alo[16*136];
  int tid = threadIdx.x;
  int n0 = blockIdx.x*16;
  if (tid < 256){
    int node = tid>>4, chunk = tid&15;
    int n = n0 + node;
    int f = chunk*8;
    float in7[7];
    in7[0]=r[n];
    #pragma unroll
    for (int k=0;k<6;++k) in7[1+k]=v[n*6+k];
    half8 ah, al;
    #pragma unroll
    for (int j=0;j<8;++j){
      float z = b1e[f+j];
      #pragma unroll
      for (int k=0;k<7;++k) z += in7[k]*W1[k*HD + f+j];
      float a = fmaxf(z, 0.f);
      _Float16 h = (_Float16)a;
      ah[j] = h; al[j] = (_Float16)(a - (float)h);
    }
    *(half8*)&Ahi[node*136 + f] = ah;
    *(half8*)&Alo[node*136 + f] = al;
  }
  int wid = tid>>6, lane = tid&63, g = lane>>4, c = lane&15;
  int col = 16*wid + c;
  half8 bh[4], bl[4];
  #pragma unroll
  for (int ks=0; ks<4; ++ks){
    half8 fh, fl;
    #pragma unroll
    for (int j=0;j<8;++j){
      float w = W2[(size_t)(ks*32 + g*8 + j)*HD + col];
      _Float16 h = (_Float16)w;
      fh[j]=h; fl[j]=(_Float16)(w - (float)h);
    }
    bh[ks]=fh; bl[ks]=fl;
  }
  float b2c = b2[col];
  f32x4 zero4 = {0.f,0.f,0.f,0.f};
  __syncthreads();
  f32x4 d = zero4;
  #pragma unroll
  for (int ks=0; ks<4; ++ks){
    half8 ah = *(const half8*)&Ahi[c*136 + ks*32 + g*8];
    half8 al = *(const half8*)&Alo[c*136 + ks*32 + g*8];
    d = __builtin_amdgcn_mfma_f32_16x16x32_f16(ah, bh[ks], d, 0,0,0);
    d = __builtin_amdgcn_mfma_f32_16x16x32_f16(al, bh[ks], d, 0,0,0);
    d = __builtin_amdgcn_mfma_f32_16x16x32_f16(ah, bl[ks], d, 0,0,0);
  }
  #pragma unroll
  for (int jj=0;jj<4;++jj){
    int n = n0 + g*4 + jj;
    hb[(size_t)n*HD + col] = fmaxf(d[jj] + b2c, 0.f);
  }
}

// ---------------- P/Q via fp16-split MFMA (k_upd template) ----------------

__global__ __launch_bounds__(512,1) void k_hW(
    const float* __restrict__ hb, const float* __restrict__ mu, const float* __restrict__ rstd,
    const float* __restrict__ v, const float* __restrict__ r,
    const float* __restrict__ W, const float* __restrict__ b1e,
    float* __restrict__ P, float* __restrict__ Q){
  __shared__ alignas(16) _Float16 Xhi[16*136];
  __shared__ alignas(16) _Float16 Xlo[16*136];
  int tid = threadIdx.x;
  int n0 = blockIdx.x*16;
  if (tid < 256){
    int node = tid>>4, chunk = tid&15;
    int n = n0 + node;
    int f = chunk*8;
    half8 xh, xl;
    #pragma unroll
    for (int j=0;j<8;++j){
      float x = (hb[(size_t)n*HD + f+j] - mu[f+j]) * rstd[f+j];
      _Float16 h = (_Float16)x;
      xh[j] = h; xl[j] = (_Float16)(x - (float)h);
    }
    *(half8*)&Xhi[node*136 + f] = xh;
    *(half8*)&Xlo[node*136 + f] = xl;
  }
  int wid = tid>>6, lane = tid&63, g = lane>>4, c = lane&15;
  int col = 16*wid + c;
  half8 bh[4], bl[4];
  #pragma unroll
  for (int ks=0; ks<4; ++ks){
    half8 fh, fl;
    #pragma unroll
    for (int j=0;j<8;++j){
      float w = W[(size_t)(ks*32 + g*8 + j)*HD + col];
      _Float16 h = (_Float16)w;
      fh[j]=h; fl[j]=(_Float16)(w - (float)h);
    }
    bh[ks]=fh; bl[ks]=fl;
  }
  float wvi[6], wvj[6];
  #pragma unroll
  for (int x=0;x<6;++x){
    wvi[x]=W[(size_t)(128+x)*HD+col];
    wvj[x]=W[(size_t)(134+x)*HD+col];
  }
  float wri=W[(size_t)140*HD+col], wrj=W[(size_t)141*HD+col];
  float b1c=b1e[col];
  f32x4 zero4 = {0.f,0.f,0.f,0.f};
  __syncthreads();
  f32x4 d = zero4;
  #pragma unroll
  for (int ks=0; ks<4; ++ks){
    half8 ah = *(const half8*)&Xhi[c*136 + ks*32 + g*8];
    half8 al = *(const half8*)&Xlo[c*136 + ks*32 + g*8];
    d = __builtin_amdgcn_mfma_f32_16x16x32_f16(ah, bh[ks], d, 0,0,0);
    d = __builtin_amdgcn_mfma_f32_16x16x32_f16(al, bh[ks], d, 0,0,0);
    d = __builtin_amdgcn_mfma_f32_16x16x32_f16(ah, bl[ks], d, 0,0,0);
  }
  #pragma unroll
  for (int jj=0;jj<4;++jj){
    int n = n0 + g*4 + jj;
    float m = d[jj];
    float p = m + b1c, q = -m;
    #pragma unroll
    for (int x=0;x<6;++x){
      float vx = v[n*6+x];
      p += vx*wvi[x]; q += vx*wvj[x];
    }
    float rn = r[n];
    p += rn*wri; q += rn*wrj;
    P[(size_t)n*HD+col]=p;
    Q[(size_t)n*HD+col]=q;
  }
}

// ---------------- edge MLP via fp16-split MFMA, wave-cooperative ----------------
// 5000 blocks x 2 dst nodes; 16-edge tiles; two-barrier protocol (round-14 body).
// W1pd fragments constructed in REGISTERS (no w1pd LDS): for lane (g,c), col f:
//   k=g*8+j slots: k0..2=Whi, k3..5=Whi, k6..8=Wlo, rest 0  (bit-identical to old LDS).

__global__ __launch_bounds__(256,2) void k_edge(
    const float* __restrict__ P, const float* __restrict__ Q,
    const float* __restrict__ pos, const float* __restrict__ dom,
    const int* __restrict__ offs, const int* __restrict__ csr,
    const float* __restrict__ Wpd, const float* __restrict__ W2, const float* __restrict__ b2,
    const float* __restrict__ invc, float* __restrict__ agg,
    float* __restrict__ zsum, float* __restrict__ zsumsq){
  __shared__ alignas(16) _Float16 a1hi[16*136];     // block-shared [edge][f]
  __shared__ alignas(16) _Float16 a1lo[16*136];
  int tid = threadIdx.x;
  if (blockIdx.x==0 && tid<HD){ zsum[tid]=0.f; zsumsq[tid]=0.f; }
  int wid = tid>>6, lane = tid&63, g = lane>>4, c = lane&15;
  int t0 = 2*wid, t1 = 2*wid+1;
  // register W1pd fragments (replaces w1pd LDS)
  half8 w1f0, w1f1;
  {
    int fA = 16*t0 + c, fB = 16*t1 + c;
    float a0=Wpd[0*HD+fA], a1v=Wpd[1*HD+fA], a2v=Wpd[2*HD+fA];
    float b0=Wpd[0*HD+fB], b1v=Wpd[1*HD+fB], b2vv=Wpd[2*HD+fB];
    #pragma unroll
    for (int j=0;j<8;++j){ w1f0[j]=(_Float16)0.f; w1f1[j]=(_Float16)0.f; }
    if (g==0){
      _Float16 h0=(_Float16)a0, h1=(_Float16)a1v, h2=(_Float16)a2v;
      w1f0[0]=h0; w1f0[1]=h1; w1f0[2]=h2;
      w1f0[3]=h0; w1f0[4]=h1; w1f0[5]=h2;
      w1f0[6]=(_Float16)(a0-(float)h0);
      w1f0[7]=(_Float16)(a1v-(float)h1);
      _Float16 k0=(_Float16)b0, k1=(_Float16)b1v, k2=(_Float16)b2vv;
      w1f1[0]=k0; w1f1[1]=k1; w1f1[2]=k2;
      w1f1[3]=k0; w1f1[4]=k1; w1f1[5]=k2;
      w1f1[6]=(_Float16)(b0-(float)k0);
      w1f1[7]=(_Float16)(b1v-(float)k1);
    } else if (g==1){
      _Float16 h2=(_Float16)a2v, k2=(_Float16)b2vv;
      w1f0[0]=(_Float16)(a2v-(float)h2);
      w1f1[0]=(_Float16)(b2vv-(float)k2);
    }
  }
  half8 w2h[4][2], w2l[4][2];
  #pragma unroll
  for (int ks=0; ks<4; ++ks){
    #pragma unroll
    for (int tt=0; tt<2; ++tt){
      int col = 16*(2*wid+tt) + c;
      half8 fh, fl;
      #pragma unroll
      for (int j=0;j<8;++j){
        float w = W2[(ks*32 + g*8 + j)*HD + col];
        _Float16 h = (_Float16)w;
        fh[j] = h;
        fl[j] = (_Float16)(w - (float)h);
      }
      w2h[ks][tt] = fh;
      w2l[ks][tt] = fl;
    }
  }
  float b2v0 = b2[16*t0 + c], b2v1 = b2[16*t1 + c];
  float dm0=dom[0], dm1=dom[1], dm2=dom[2];
  f32x4 zero4 = {0.f,0.f,0.f,0.f};
  int n0 = blockIdx.x*2;
  for (int n = n0; n < n0+2; ++n){
    f32x4 pv0 = *(const f32x4*)(P + (size_t)n*HD + 16*t0 + 4*g);
    f32x4 pv1 = *(const f32x4*)(P + (size_t)n*HD + 16*t1 + 4*g);
    float pn0=pos[n*3+0], pn1=pos[n*3+1], pn2=pos[n*3+2];
    float acc0=0.f, acc1=0.f;
    int ib=offs[n], ie=offs[n+1];
    for (int base=ib; base<ie; base+=16){
      int nb = ie - base; if (nb>16) nb = 16;
      int sA = csr[base + ((c<nb)? c : nb-1)];
      float q0=pos[sA*3+0], q1=pos[sA*3+1], q2=pos[sA*3+2];
      float pd0,pd1,pd2;
      { float diff,sh,ds;
        diff=pn0-q0; sh=(pn0<q0)?-dm0:dm0; ds=diff-sh; pd0=(fabsf(diff)<fabsf(ds))?diff:ds;
        diff=pn1-q1; sh=(pn1<q1)?-dm1:dm1; ds=diff-sh; pd1=(fabsf(diff)<fabsf(ds))?diff:ds;
        diff=pn2-q2; sh=(pn2<q2)?-dm2:dm2; ds=diff-sh; pd2=(fabsf(diff)<fabsf(ds))?diff:ds;
      }
      _Float16 p0h = (_Float16)pd0, p1h = (_Float16)pd1, p2h = (_Float16)pd2;
      _Float16 p0l = (_Float16)(pd0 - (float)p0h);
      _Float16 p1l = (_Float16)(pd1 - (float)p1h);
      _Float16 p2l = (_Float16)(pd2 - (float)p2h);
      half8 pdf;
      #pragma unroll
      for (int j=0;j<8;++j) pdf[j]=(_Float16)0.f;
      if (g==0){ pdf[0]=p0h; pdf[1]=p1h; pdf[2]=p2h; pdf[3]=p0l; pdf[4]=p1l; pdf[5]=p2l; pdf[6]=p0h; pdf[7]=p1h; }
      else if (g==1){ pdf[0]=p2h; }
      f32x4 d0 = __builtin_amdgcn_mfma_f32_16x16x32_f16(w1f0, pdf, zero4, 0,0,0);
      f32x4 d1 = __builtin_amdgcn_mfma_f32_16x16x32_f16(w1f1, pdf, zero4, 0,0,0);
      const float* Qs = Q + (size_t)sA*HD;
      f32x4 qv0 = *(const f32x4*)(Qs + 16*t0 + 4*g);
      f32x4 qv1 = *(const f32x4*)(Qs + 16*t1 + 4*g);
      half4v h0, l0, h1, l1;
      #pragma unroll
      for (int j=0;j<4;++j){
        float a = fmaxf(d0[j] + pv0[j] + qv0[j], 0.f);
        _Float16 hh = (_Float16)a;
        h0[j] = hh; l0[j] = (_Float16)(a - (float)hh);
        float b = fmaxf(d1[j] + pv1[j] + qv1[j], 0.f);
        _Float16 hb2 = (_Float16)b;
        h1[j] = hb2; l1[j] = (_Float16)(b - (float)hb2);
      }
      *(half4v*)&a1hi[c*136 + 16*t0 + 4*g] = h0;
      *(half4v*)&a1lo[c*136 + 16*t0 + 4*g] = l0;
      *(half4v*)&a1hi[c*136 + 16*t1 + 4*g] = h1;
      *(half4v*)&a1lo[c*136 + 16*t1 + 4*g] = l1;
      __syncthreads();
      f32x4 m0 = zero4, m1 = zero4;
      #pragma unroll
      for (int ks=0; ks<4; ++ks){
        half8 ah = *(const half8*)&a1hi[c*136 + ks*32 + g*8];
        half8 al = *(const half8*)&a1lo[c*136 + ks*32 + g*8];
        m0 = __builtin_amdgcn_mfma_f32_16x16x32_f16(ah, w2h[ks][0], m0, 0,0,0);
        m0 = __builtin_amdgcn_mfma_f32_16x16x32_f16(al, w2h[ks][0], m0, 0,0,0);
        m0 = __builtin_amdgcn_mfma_f32_16x16x32_f16(ah, w2l[ks][0], m0, 0,0,0);
        m1 = __builtin_amdgcn_mfma_f32_16x16x32_f16(ah, w2h[ks][1], m1, 0,0,0);
        m1 = __builtin_amdgcn_mfma_f32_16x16x32_f16(al, w2h[ks][1], m1, 0,0,0);
        m1 = __builtin_amdgcn_mfma_f32_16x16x32_f16(ah, w2l[ks][1], m1, 0,0,0);
      }
      if (nb == 16){
        acc0 += fmaxf(m0[0]+b2v0,0.f)+fmaxf(m0[1]+b2v0,0.f)+fmaxf(m0[2]+b2v0,0.f)+fmaxf(m0[3]+b2v0,0.f);
        acc1 += fmaxf(m1[0]+b2v1,0.f)+fmaxf(m1[1]+b2v1,0.f)+fmaxf(m1[2]+b2v1,0.f)+fmaxf(m1[3]+b2v1,0.f);
      } else {
        #pragma unroll
        for (int j=0;j<4;++j){
          if (4*g+j < nb){
            acc0 += fmaxf(m0[j]+b2v0, 0.f);
            acc1 += fmaxf(m1[j]+b2v1, 0.f);
          }
        }
      }
      __syncthreads();
    }
    acc0 += __shfl_xor(acc0, 16); acc0 += __shfl_xor(acc0, 32);
    acc1 += __shfl_xor(acc1, 16); acc1 += __shfl_xor(acc1, 32);
    if (g==0){
      float ic = invc[n];
      agg[n*HD + 16*t0 + c] = acc0*ic;
      agg[n*HD + 16*t1 + c] = acc1*ic;
    }
  }
}

// ---------------- update MLP via fp16-split MFMA ----------------

__global__ __launch_bounds__(512,1) void k_upd(
    float* __restrict__ hb, const float* __restrict__ mu, const float* __restrict__ rstd,
    const float* __restrict__ agg,
    const float* __restrict__ U1, const float* __restrict__ b1e,
    const float* __restrict__ U2, const float* __restrict__ bs2,
    float* __restrict__ sum, float* __restrict__ sumsq){
  __shared__ alignas(16) _Float16 Xhi[16*264];
  __shared__ alignas(16) _Float16 Xlo[16*264];
  __shared__ alignas(16) _Float16 Ahi[16*136];
  __shared__ alignas(16) _Float16 Alo[16*136];
  int tid = threadIdx.x;
  int n0 = blockIdx.x*16;
  {
    int node = tid>>5, chunk = tid&31;
    int n = n0 + node;
    int f = chunk*8;
    half8 xh, xl;
    if (f < 128){
      #pragma unroll
      for (int j=0;j<8;++j){
        float x = (hb[(size_t)n*HD + f+j] - mu[f+j]) * rstd[f+j];
        _Float16 h = (_Float16)x;
        xh[j] = h; xl[j] = (_Float16)(x - (float)h);
      }
    } else {
      #pragma unroll
      for (int j=0;j<8;++j){
        float x = agg[(size_t)n*HD + (f-128)+j];
        _Float16 h = (_Float16)x;
        xh[j] = h; xl[j] = (_Float16)(x - (float)h);
      }
    }
    *(half8*)&Xhi[node*264 + f] = xh;
    *(half8*)&Xlo[node*264 + f] = xl;
  }
  int wid = tid>>6, lane = tid&63, g = lane>>4, c = lane&15;
  int col = 16*wid + c;
  half8 b1h[8], b1l[8], b2h[4], b2l[4];
  #pragma unroll
  for (int ks=0; ks<8; ++ks){
    half8 fh, fl;
    #pragma unroll
    for (int j=0;j<8;++j){
      float w = U1[(size_t)(ks*32 + g*8 + j)*HD + col];
      _Float16 h = (_Float16)w;
      fh[j]=h; fl[j]=(_Float16)(w - (float)h);
    }
    b1h[ks]=fh; b1l[ks]=fl;
  }
  #pragma unroll
  for (int ks=0; ks<4; ++ks){
    half8 fh, fl;
    #pragma unroll
    for (int j=0;j<8;++j){
      float w = U2[(size_t)(ks*32 + g*8 + j)*HD + col];
      _Float16 h = (_Float16)w;
      fh[j]=h; fl[j]=(_Float16)(w - (float)h);
    }
    b2h[ks]=fh; b2l[ks]=fl;
  }
  f32x4 zero4 = {0.f,0.f,0.f,0.f};
  __syncthreads();
  f32x4 d = zero4;
  #pragma unroll
  for (int ks=0; ks<8; ++ks){
    half8 ah = *(const half8*)&Xhi[c*264 + ks*32 + g*8];
    half8 al = *(const half8*)&Xlo[c*264 + ks*32 + g*8];
    d = __builtin_amdgcn_mfma_f32_16x16x32_f16(ah, b1h[ks], d, 0,0,0);
    d = __builtin_amdgcn_mfma_f32_16x16x32_f16(al, b1h[ks], d, 0,0,0);
    d = __builtin_amdgcn_mfma_f32_16x16x32_f16(ah, b1l[ks], d, 0,0,0);
  }
  {
    float bb = b1e[col];
    #pragma unroll
    for (int jj=0;jj<4;++jj){
      float a = fmaxf(d[jj] + bb, 0.f);
      _Float16 h = (_Float16)a;
      Ahi[(g*4+jj)*136 + col] = h;
      Alo[(g*4+jj)*136 + col] = (_Float16)(a - (float)h);
    }
  }
  __syncthreads();
  f32x4 u = zero4;
  #pragma unroll
  for (int ks=0; ks<4; ++ks){
    half8 ah = *(const half8*)&Ahi[c*136 + ks*32 + g*8];
    half8 al = *(const half8*)&Alo[c*136 + ks*32 + g*8];
    u = __builtin_amdgcn_mfma_f32_16x16x32_f16(ah, b2h[ks], u, 0,0,0);
    u = __builtin_amdgcn_mfma_f32_16x16x32_f16(al, b2h[ks], u, 0,0,0);
    u = __builtin_amdgcn_mfma_f32_16x16x32_f16(ah, b2l[ks], u, 0,0,0);
  }
  float bc = bs2[col];
  float mc = mu[col], rc = rstd[col];
  float s=0.f, q=0.f;
  #pragma unroll
  for (int jj=0;jj<4;++jj){
    int n = n0 + g*4 + jj;
    float hn = (hb[(size_t)n*HD + col] - mc)*rc;
    float b0 = hn + fmaxf(u[jj] + bc, 0.f);
    hb[(size_t)n*HD + col] = b0;
    s += b0; q += b0*b0;
  }
  s += __shfl_xor(s,16); s += __shfl_xor(s,32);
  q += __shfl_xor(q,16); q += __shfl_xor(q,32);
  if (g==0){
    atomicAdd(&sum[col], s);
    atomicAdd(&sumsq[col], q);
  }
}

__global__ void k_normfin(const float* __restrict__ sum, const float* __restrict__ sumsq,
                          float* __restrict__ mu, float* __restrict__ rstd){
  int t=threadIdx.x;
  float m = sum[t]*(1.0f/NN);
  float var = sumsq[t]*(1.0f/NN) - m*m;
  mu[t]=m;
  rstd[t]=rsqrtf(fmaxf(var,0.0f)+EPSV);
}

// ---------------- decoder via fp16-split MFMA (k_upd template) ----------------

__global__ __launch_bounds__(512,1) void k_out(
    const float* __restrict__ hb, const float* __restrict__ mu, const float* __restrict__ rstd,
    const float* __restrict__ pos, const float* __restrict__ v,
    const float* __restrict__ W1, const float* __restrict__ b1,
    const float* __restrict__ W2, const float* __restrict__ b2,
    const float* __restrict__ domn, float* __restrict__ out){
  __shared__ alignas(16) _Float16 Xhi[16*136];
  __shared__ alignas(16) _Float16 Xlo[16*136];
  __shared__ alignas(16) _Float16 Ahi[16*136];
  __shared__ alignas(16) _Float16 Alo[16*136];
  int tid = threadIdx.x;
  int n0 = blockIdx.x*16;
  if (tid < 256){
    int node = tid>>4, chunk = tid&15;
    int n = n0 + node;
    int f = chunk*8;
    half8 xh, xl;
    #pragma unroll
    for (int j=0;j<8;++j){
      float x = (hb[(size_t)n*HD + f+j] - mu[f+j]) * rstd[f+j];
      _Float16 h = (_Float16)x;
      xh[j] = h; xl[j] = (_Float16)(x - (float)h);
    }
    *(half8*)&Xhi[node*136 + f] = xh;
    *(half8*)&Xlo[node*136 + f] = xl;
  }
  int wid = tid>>6, lane = tid&63, g = lane>>4, c = lane&15;
  int col = 16*wid + c;
  half8 bh[4], bl[4];
  #pragma unroll
  for (int ks=0; ks<4; ++ks){
    half8 fh, fl;
    #pragma unroll
    for (int j=0;j<8;++j){
      float w = W1[(size_t)(ks*32 + g*8 + j)*HD + col];
      _Float16 h = (_Float16)w;
      fh[j]=h; fl[j]=(_Float16)(w - (float)h);
    }
    bh[ks]=fh; bl[ks]=fl;
  }
  half8 w9h[4], w9l[4];
  if (wid==0){
    #pragma unroll
    for (int ks=0; ks<4; ++ks){
      half8 fh, fl;
      #pragma unroll
      for (int j=0;j<8;++j){
        float w = (c<9)? W2[(size_t)(ks*32 + g*8 + j)*9 + c] : 0.f;
        _Float16 h = (_Float16)w;
        fh[j]=h; fl[j]=(_Float16)(w - (float)h);
      }
      w9h[ks]=fh; w9l[ks]=fl;
    }
  }
  float b1c = b1[col];
  f32x4 zero4 = {0.f,0.f,0.f,0.f};
  __syncthreads();
  f32x4 d = zero4;
  #pragma unroll
  for (int ks=0; ks<4; ++ks){
    half8 ah = *(const half8*)&Xhi[c*136 + ks*32 + g*8];
    half8 al = *(const half8*)&Xlo[c*136 + ks*32 + g*8];
    d = __builtin_amdgcn_mfma_f32_16x16x32_f16(ah, bh[ks], d, 0,0,0);
    d = __builtin_amdgcn_mfma_f32_16x16x32_f16(al, bh[ks], d, 0,0,0);
    d = __builtin_amdgcn_mfma_f32_16x16x32_f16(ah, bl[ks], d, 0,0,0);
  }
  #pragma unroll
  for (int jj=0;jj<4;++jj){
    float a = fmaxf(d[jj] + b1c, 0.f);
    _Float16 h = (_Float16)a;
    Ahi[(g*4+jj)*136 + col] = h;
    Alo[(g*4+jj)*136 + col] = (_Float16)(a - (float)h);
  }
  __syncthreads();
  if (wid==0){
    f32x4 u = zero4;
    #pragma unroll
    for (int ks=0; ks<4; ++ks){
      half8 ah = *(const half8*)&Ahi[c*136 + ks*32 + g*8];
      half8 al = *(const half8*)&Alo[c*136 + ks*32 + g*8];
      u = __builtin_amdgcn_mfma_f32_16x16x32_f16(ah, w9h[ks], u, 0,0,0);
      u = __builtin_amdgcn_mfma_f32_16x16x32_f16(al, w9h[ks], u, 0,0,0);
      u = __builtin_amdgcn_mfma_f32_16x16x32_f16(ah, w9l[ks], u, 0,0,0);
    }
    if (c < 9){
      float bc = b2[c];
      #pragma unroll
      for (int jj=0;jj<4;++jj){
        int n = n0 + g*4 + jj;
        float p = u[jj] + bc;
        if (c < 3){
          p += pos[n*3+c];
          float dd = domn[c];
          p = p - floorf(p/dd)*dd;
          out[n*3+c] = p;
        } else {
          p += v[n*6 + (c-3)];
          out[3*NN + n*6 + (c-3)] = p;
        }
      }
    }
  }
}

__global__ void k_macro(const float* __restrict__ sum, const float* __restrict__ mu, const float* __restrict__ rstd,
                        const float* __restrict__ W1, const float* __restrict__ b1,
                        const float* __restrict__ W2, const float* __restrict__ b2,
                        float* __restrict__ out){
  __shared__ float hm[HD];
  __shared__ float as[HD];
  int t=threadIdx.x;
  hm[t] = (sum[t]*(1.0f/NN) - mu[t])*rstd[t];
  __syncthreads();
  float z=b1[t];
  for (int k=0;k<HD;++k) z += hm[k]*W1[k*HD+t];
  as[t]=relu_(z);
  __syncthreads();
  if (t<3){
    float p=b2[t];
    for (int k=0;k<HD;++k) p += as[k]*W2[k*3+t];
    out[9*NN+t]=p;
  }
}

// ---------------- host launch ----------------

extern "C" void kernel_launch(void* const* d_in, const int* in_sizes, int n_in,
                              void* d_out, int out_size, void* d_ws, size_t ws_size,
                              hipStream_t stream) {
  const float* v    = (const float*)d_in[0];
  const float* pos  = (const float*)d_in[1];
  const float* r    = (const float*)d_in[2];
  const float* dom  = (const float*)d_in[3];
  const float* tt   = (const float*)d_in[4];
  const float* xg   = (const float*)d_in[5];
  const float* domn = (const float*)d_in[6];
  const float* tn   = (const float*)d_in[7];
  const int*   eidx = (const int*)d_in[8];
  const float* embW1 = (const float*)d_in[10];
  const float* embB1 = (const float*)d_in[11];
  const float* embW2 = (const float*)d_in[12];
  const float* embB2 = (const float*)d_in[13];
  const float* msgW1 = (const float*)d_in[14];
  const float* msgB1 = (const float*)d_in[15];
  const float* msgW2 = (const float*)d_in[16];
  const float* msgB2 = (const float*)d_in[17];
  const float* updW1 = (const float*)d_in[18];
  const float* updB1 = (const float*)d_in[19];
  const float* updW2 = (const float*)d_in[20];
  const float* updB2 = (const float*)d_in[21];
  const float* outW1 = (const float*)d_in[22];
  const float* outB1 = (const float*)d_in[23];
  const float* outW2 = (const float*)d_in[24];
  const float* outB2 = (const float*)d_in[25];
  const float* macW1 = (const float*)d_in[26];
  const float* macB1 = (const float*)d_in[27];
  const float* macW2 = (const float*)d_in[28];
  const float* macB2 = (const float*)d_in[29];
  float* out = (float*)d_out;
  float* ws  = (float*)d_ws;

  float* hb    = ws;
  float* P     = ws + 1280000;
  float* Q     = ws + 2560000;
  float* agg   = ws + 3840000;
  float* invc  = ws + 5120000;
  float* b1eff = ws + 5130000;   // 13*128
  float* sum   = ws + 5131664;
  float* sumsq = ws + 5131792;
  float* mu    = ws + 5131920;
  float* rstd  = ws + 5132048;
  int* counts  = (int*)(ws + 5132304);
  int* offs    = counts + NN;       // NN+1
  int* cursor  = offs + NN + 1;
  int* csr     = cursor + NN;       // NE

  const int* srcA = eidx;
  const int* dstA = eidx + NE;

  hipMemsetAsync(counts, 0, NN*sizeof(int), stream);
  hipMemsetAsync(cursor, 0, NN*sizeof(int), stream);

  k_degree<<<(NE+255)/256, 256, 0, stream>>>(dstA, counts);
  k_scan<<<1, 1024, 0, stream>>>(counts, offs, invc);
  k_place<<<(NE+255)/256, 256, 0, stream>>>(srcA, dstA, offs, cursor, csr);
  k_biasfold<<<14, 128, 0, stream>>>(dom, tt, xg, domn, tn, embW1, embB1, msgW1, msgB1, updW1, updB1,
                                     b1eff, mu, rstd);
  k_embed<<<625, 512, 0, stream>>>(r, v, embW1, b1eff, embW2, embB2, hb);

  for (int l=0; l<NL; ++l){
    k_hW<<<625,512,0,stream>>>(hb, mu, rstd, v, r, msgW1 + (size_t)l*157*HD, b1eff + (1+l)*HD, P, Q);
    k_edge<<<5000,256,0,stream>>>(P, Q, pos, dom, offs, csr,
        msgW1 + ((size_t)l*157+142)*HD,
        msgW2 + (size_t)l*HD*HD, msgB2 + l*HD, invc, agg, sum, sumsq);
    k_upd<<<625,512,0,stream>>>(hb, mu, rstd, agg,
        updW1 + (size_t)l*268*HD, b1eff + (7+l)*HD,
        updW2 + (size_t)l*HD*HD, updB2 + l*HD, sum, sumsq);
    k_normfin<<<1,128,0,stream>>>(sum, sumsq, mu, rstd);
  }

  k_out<<<625,512,0,stream>>>(hb, mu, rstd, pos, v, outW1, outB1, outW2, outB2, domn, out);
  k_macro<<<1,128,0,stream>>>(sum, mu, rstd, macW1, macB1, macW2, macB2, out);
}

// Round 17
// 819.852 us; speedup vs baseline: 1.1344x; 1.0172x over previous
//
#include <hip/hip_runtime.h>
#include <hip/hip_bf16.h>

#define NN 10000
#define NE 320000
#define HD 128
#define NL 6
#define EPSV 1e-5f

typedef _Float16 half8  __attribute__((ext_vector_type(8)));
typedef _Float16 half4v __attribute__((ext_vector_type(4)));
typedef float    f32x4  __attribute__((ext_vector_type(4)));

__device__ __forceinline__ float relu_(float x){ return fmaxf(x, 0.0f); }

// LDS-only barrier: drain ds ops, leave global loads in flight (HK/8-phase primitive)
#define LGKM_BAR() do { asm volatile("s_waitcnt lgkmcnt(0)" ::: "memory"); __builtin_amdgcn_s_barrier(); } while(0)

// ---------------- degree / scan / place (CSR build) ----------------

__global__ void k_degree(const int* __restrict__ dst, int* __restrict__ counts){
  int e = blockIdx.x*256 + threadIdx.x;
  if (e < NE) atomicAdd(&counts[dst[e]], 1);
}

__global__ void k_scan(const int* __restrict__ counts, int* __restrict__ offs, float* __restrict__ invc){
  __shared__ int lds[1024];
  __shared__ int base_s;
  int tid = threadIdx.x;
  if (tid==0) base_s = 0;
  __syncthreads();
  for (int start=0; start<NN; start+=1024){
    int i = start+tid;
    int vv = (i<NN)? counts[i] : 0;
    lds[tid]=vv; __syncthreads();
    for (int off=1; off<1024; off<<=1){
      int t = (tid>=off)? lds[tid-off] : 0;
      __syncthreads();
      lds[tid] += t;
      __syncthreads();
    }
    int incl = lds[tid];
    if (i<NN){
      offs[i] = base_s + incl - vv;
      invc[i] = 1.0f / fmaxf((float)vv, 1.0f);
    }
    __syncthreads();
    if (tid==1023) base_s += lds[1023];
    __syncthreads();
  }
  if (tid==0) offs[NN] = base_s;
}

__global__ void k_place(const int* __restrict__ src, const int* __restrict__ dst,
                        const int* __restrict__ offs, int* __restrict__ cursor, int* __restrict__ csr){
  int e = blockIdx.x*256 + threadIdx.x;
  if (e < NE){
    int d = dst[e];
    int p = atomicAdd(&cursor[d], 1);
    csr[offs[d]+p] = src[e];
  }
}

// ---------------- fold gf into first-layer biases + init mu/rstd ----------------

__global__ void k_biasfold(const float* __restrict__ dom, const float* __restrict__ tt,
                           const float* __restrict__ xg, const float* __restrict__ domn,
                           const float* __restrict__ tn,
                           const float* __restrict__ embW1, const float* __restrict__ embB1,
                           const float* __restrict__ msgW1, const float* __restrict__ msgB1,
                           const float* __restrict__ updW1, const float* __restrict__ updB1,
                           float* __restrict__ b1eff, float* __restrict__ mu, float* __restrict__ rstd){
  float gf[12];
  gf[0]=dom[0]; gf[1]=dom[1]; gf[2]=dom[2]; gf[3]=tt[0];
  gf[4]=xg[0]; gf[5]=xg[1]; gf[6]=xg[2]; gf[7]=xg[3];
  gf[8]=domn[0]; gf[9]=domn[1]; gf[10]=domn[2]; gf[11]=tn[0];
  int b = blockIdx.x, t = threadIdx.x;
  if (b==0){
    float s = embB1[t];
    #pragma unroll
    for (int k=0;k<12;++k) s += gf[k]*embW1[(7+k)*HD + t];
    b1eff[t] = s;
  } else if (b<=6){
    int l=b-1;
    float s = msgB1[l*HD+t];
    #pragma unroll
    for (int k=0;k<12;++k) s += gf[k]*msgW1[((size_t)l*157 + 145+k)*HD + t];
    b1eff[(1+l)*HD + t] = s;
  } else if (b<=12){
    int l=b-7;
    float s = updB1[l*HD+t];
    #pragma unroll
    for (int k=0;k<12;++k) s += gf[k]*updW1[((size_t)l*268 + 256+k)*HD + t];
    b1eff[(7+l)*HD + t] = s;
  } else {
    mu[t] = 0.f;
    rstd[t] = 1.f;
  }
}

// ---------------- embedding via fp16-split MFMA (k_upd template) ----------------

__global__ __launch_bounds__(512,1) void k_embed(
    const float* __restrict__ r, const float* __restrict__ v,
    const float* __restrict__ W1, const float* __restrict__ b1e,
    const float* __restrict__ W2, const float* __restrict__ b2,
    float* __restrict__ hb){
  __shared__ alignas(16) _Float16 Ahi[16*136];
  __shared__ alignas(16) _Float16 Alo[16*136];
  int tid = threadIdx.x;
  int n0 = blockIdx.x*16;
  if (tid < 256){
    int node = tid>>4, chunk = tid&15;
    int n = n0 + node;
    int f = chunk*8;
    float in7[7];
    in7[0]=r[n];
    #pragma unroll
    for (int k=0;k<6;++k) in7[1+k]=v[n*6+k];
    half8 ah, al;
    #pragma unroll
    for (int j=0;j<8;++j){
      float z = b1e[f+j];
      #pragma unroll
      for (int k=0;k<7;++k) z += in7[k]*W1[k*HD + f+j];
      float a = fmaxf(z, 0.f);
      _Float16 h = (_Float16)a;
      ah[j] = h; al[j] = (_Float16)(a - (float)h);
    }
    *(half8*)&Ahi[node*136 + f] = ah;
    *(half8*)&Alo[node*136 + f] = al;
  }
  int wid = tid>>6, lane = tid&63, g = lane>>4, c = lane&15;
  int col = 16*wid + c;
  half8 bh[4], bl[4];
  #pragma unroll
  for (int ks=0; ks<4; ++ks){
    half8 fh, fl;
    #pragma unroll
    for (int j=0;j<8;++j){
      float w = W2[(size_t)(ks*32 + g*8 + j)*HD + col];
      _Float16 h = (_Float16)w;
      fh[j]=h; fl[j]=(_Float16)(w - (float)h);
    }
    bh[ks]=fh; bl[ks]=fl;
  }
  float b2c = b2[col];
  f32x4 zero4 = {0.f,0.f,0.f,0.f};
  __syncthreads();
  f32x4 d = zero4;
  #pragma unroll
  for (int ks=0; ks<4; ++ks){
    half8 ah = *(const half8*)&Ahi[c*136 + ks*32 + g*8];
    half8 al = *(const half8*)&Alo[c*136 + ks*32 + g*8];
    d = __builtin_amdgcn_mfma_f32_16x16x32_f16(ah, bh[ks], d, 0,0,0);
    d = __builtin_amdgcn_mfma_f32_16x16x32_f16(al, bh[ks], d, 0,0,0);
    d = __builtin_amdgcn_mfma_f32_16x16x32_f16(ah, bl[ks], d, 0,0,0);
  }
  #pragma unroll
  for (int jj=0;jj<4;++jj){
    int n = n0 + g*4 + jj;
    hb[(size_t)n*HD + col] = fmaxf(d[jj] + b2c, 0.f);
  }
}

// ---------------- P/Q via fp16-split MFMA (k_upd template) ----------------

__global__ __launch_bounds__(512,1) void k_hW(
    const float* __restrict__ hb, const float* __restrict__ mu, const float* __restrict__ rstd,
    const float* __restrict__ v, const float* __restrict__ r,
    const float* __restrict__ W, const float* __restrict__ b1e,
    float* __restrict__ P, float* __restrict__ Q){
  __shared__ alignas(16) _Float16 Xhi[16*136];
  __shared__ alignas(16) _Float16 Xlo[16*136];
  int tid = threadIdx.x;
  int n0 = blockIdx.x*16;
  if (tid < 256){
    int node = tid>>4, chunk = tid&15;
    int n = n0 + node;
    int f = chunk*8;
    half8 xh, xl;
    #pragma unroll
    for (int j=0;j<8;++j){
      float x = (hb[(size_t)n*HD + f+j] - mu[f+j]) * rstd[f+j];
      _Float16 h = (_Float16)x;
      xh[j] = h; xl[j] = (_Float16)(x - (float)h);
    }
    *(half8*)&Xhi[node*136 + f] = xh;
    *(half8*)&Xlo[node*136 + f] = xl;
  }
  int wid = tid>>6, lane = tid&63, g = lane>>4, c = lane&15;
  int col = 16*wid + c;
  half8 bh[4], bl[4];
  #pragma unroll
  for (int ks=0; ks<4; ++ks){
    half8 fh, fl;
    #pragma unroll
    for (int j=0;j<8;++j){
      float w = W[(size_t)(ks*32 + g*8 + j)*HD + col];
      _Float16 h = (_Float16)w;
      fh[j]=h; fl[j]=(_Float16)(w - (float)h);
    }
    bh[ks]=fh; bl[ks]=fl;
  }
  float wvi[6], wvj[6];
  #pragma unroll
  for (int x=0;x<6;++x){
    wvi[x]=W[(size_t)(128+x)*HD+col];
    wvj[x]=W[(size_t)(134+x)*HD+col];
  }
  float wri=W[(size_t)140*HD+col], wrj=W[(size_t)141*HD+col];
  float b1c=b1e[col];
  f32x4 zero4 = {0.f,0.f,0.f,0.f};
  __syncthreads();
  f32x4 d = zero4;
  #pragma unroll
  for (int ks=0; ks<4; ++ks){
    half8 ah = *(const half8*)&Xhi[c*136 + ks*32 + g*8];
    half8 al = *(const half8*)&Xlo[c*136 + ks*32 + g*8];
    d = __builtin_amdgcn_mfma_f32_16x16x32_f16(ah, bh[ks], d, 0,0,0);
    d = __builtin_amdgcn_mfma_f32_16x16x32_f16(al, bh[ks], d, 0,0,0);
    d = __builtin_amdgcn_mfma_f32_16x16x32_f16(ah, bl[ks], d, 0,0,0);
  }
  #pragma unroll
  for (int jj=0;jj<4;++jj){
    int n = n0 + g*4 + jj;
    float m = d[jj];
    float p = m + b1c, q = -m;
    #pragma unroll
    for (int x=0;x<6;++x){
      float vx = v[n*6+x];
      p += vx*wvi[x]; q += vx*wvj[x];
    }
    float rn = r[n];
    p += rn*wri; q += rn*wrj;
    P[(size_t)n*HD+col]=p;
    Q[(size_t)n*HD+col]=q;
  }
}

// ---------------- edge MLP via fp16-split MFMA, pipelined gathers ----------------
// 5000 blocks x 2 dst nodes; 16-edge tiles; two LGKM-only barriers per tile
// (global loads stay in flight across barriers). Split prefetch: next tile's
// csr issued before GEMM1; next tile's pos/Q issued after barrier #1 (under GEMM2).

__global__ __launch_bounds__(256,2) void k_edge(
    const float* __restrict__ P, const float* __restrict__ Q,
    const float* __restrict__ pos, const float* __restrict__ dom,
    const int* __restrict__ offs, const int* __restrict__ csr,
    const float* __restrict__ Wpd, const float* __restrict__ W2, const float* __restrict__ b2,
    const float* __restrict__ invc, float* __restrict__ agg,
    float* __restrict__ zsum, float* __restrict__ zsumsq){
  __shared__ alignas(16) _Float16 a1hi[16*136];     // block-shared [edge][f]
  __shared__ alignas(16) _Float16 a1lo[16*136];
  int tid = threadIdx.x;
  if (blockIdx.x==0 && tid<HD){ zsum[tid]=0.f; zsumsq[tid]=0.f; }
  int wid = tid>>6, lane = tid&63, g = lane>>4, c = lane&15;
  int t0 = 2*wid, t1 = 2*wid+1;
  // register W1pd fragments (bit-identical to the old w1pd LDS contents)
  half8 w1f0, w1f1;
  {
    int fA = 16*t0 + c, fB = 16*t1 + c;
    float a0=Wpd[0*HD+fA], a1v=Wpd[1*HD+fA], a2v=Wpd[2*HD+fA];
    float b0=Wpd[0*HD+fB], b1v=Wpd[1*HD+fB], b2vv=Wpd[2*HD+fB];
    #pragma unroll
    for (int j=0;j<8;++j){ w1f0[j]=(_Float16)0.f; w1f1[j]=(_Float16)0.f; }
    if (g==0){
      _Float16 h0=(_Float16)a0, h1=(_Float16)a1v, h2=(_Float16)a2v;
      w1f0[0]=h0; w1f0[1]=h1; w1f0[2]=h2;
      w1f0[3]=h0; w1f0[4]=h1; w1f0[5]=h2;
      w1f0[6]=(_Float16)(a0-(float)h0);
      w1f0[7]=(_Float16)(a1v-(float)h1);
      _Float16 k0=(_Float16)b0, k1=(_Float16)b1v, k2=(_Float16)b2vv;
      w1f1[0]=k0; w1f1[1]=k1; w1f1[2]=k2;
      w1f1[3]=k0; w1f1[4]=k1; w1f1[5]=k2;
      w1f1[6]=(_Float16)(b0-(float)k0);
      w1f1[7]=(_Float16)(b1v-(float)k1);
    } else if (g==1){
      _Float16 h2=(_Float16)a2v, k2=(_Float16)b2vv;
      w1f0[0]=(_Float16)(a2v-(float)h2);
      w1f1[0]=(_Float16)(b2vv-(float)k2);
    }
  }
  half8 w2h[4][2], w2l[4][2];
  #pragma unroll
  for (int ks=0; ks<4; ++ks){
    #pragma unroll
    for (int tt=0; tt<2; ++tt){
      int col = 16*(2*wid+tt) + c;
      half8 fh, fl;
      #pragma unroll
      for (int j=0;j<8;++j){
        float w = W2[(ks*32 + g*8 + j)*HD + col];
        _Float16 h = (_Float16)w;
        fh[j] = h;
        fl[j] = (_Float16)(w - (float)h);
      }
      w2h[ks][tt] = fh;
      w2l[ks][tt] = fl;
    }
  }
  float b2v0 = b2[16*t0 + c], b2v1 = b2[16*t1 + c];
  float dm0=dom[0], dm1=dom[1], dm2=dom[2];
  f32x4 zero4 = {0.f,0.f,0.f,0.f};
  int n0 = blockIdx.x*2;
  for (int n = n0; n < n0+2; ++n){
    f32x4 pv0 = *(const f32x4*)(P + (size_t)n*HD + 16*t0 + 4*g);
    f32x4 pv1 = *(const f32x4*)(P + (size_t)n*HD + 16*t1 + 4*g);
    float pn0=pos[n*3+0], pn1=pos[n*3+1], pn2=pos[n*3+2];
    float acc0=0.f, acc1=0.f;
    int ib=offs[n], ie=offs[n+1];
    // prefetch first tile
    int sA_c=0; float qc0=0.f,qc1=0.f,qc2=0.f; f32x4 qv0_c=zero4, qv1_c=zero4;
    if (ib < ie){
      int nb0 = ie-ib; if (nb0>16) nb0=16;
      sA_c = csr[ib + ((c<nb0)? c : nb0-1)];
      qc0=pos[sA_c*3+0]; qc1=pos[sA_c*3+1]; qc2=pos[sA_c*3+2];
      qv0_c = *(const f32x4*)(Q + (size_t)sA_c*HD + 16*t0 + 4*g);
      qv1_c = *(const f32x4*)(Q + (size_t)sA_c*HD + 16*t1 + 4*g);
    }
    for (int base=ib; base<ie; base+=16){
      int nb = ie - base; if (nb>16) nb = 16;
      int bn = base + 16;
      // issue next tile's csr load early (arrives during GEMM1/z)
      int sA_n = 0;
      if (bn < ie){
        int nbn = ie - bn; if (nbn>16) nbn=16;
        sA_n = csr[bn + ((c<nbn)? c : nbn-1)];
      }
      // pd from prefetched pos
      float pd0,pd1,pd2;
      { float diff,sh,ds;
        diff=pn0-qc0; sh=(pn0<qc0)?-dm0:dm0; ds=diff-sh; pd0=(fabsf(diff)<fabsf(ds))?diff:ds;
        diff=pn1-qc1; sh=(pn1<qc1)?-dm1:dm1; ds=diff-sh; pd1=(fabsf(diff)<fabsf(ds))?diff:ds;
        diff=pn2-qc2; sh=(pn2<qc2)?-dm2:dm2; ds=diff-sh; pd2=(fabsf(diff)<fabsf(ds))?diff:ds;
      }
      _Float16 p0h = (_Float16)pd0, p1h = (_Float16)pd1, p2h = (_Float16)pd2;
      _Float16 p0l = (_Float16)(pd0 - (float)p0h);
      _Float16 p1l = (_Float16)(pd1 - (float)p1h);
      _Float16 p2l = (_Float16)(pd2 - (float)p2h);
      half8 pdf;
      #pragma unroll
      for (int j=0;j<8;++j) pdf[j]=(_Float16)0.f;
      if (g==0){ pdf[0]=p0h; pdf[1]=p1h; pdf[2]=p2h; pdf[3]=p0l; pdf[4]=p1l; pdf[5]=p2l; pdf[6]=p0h; pdf[7]=p1h; }
      else if (g==1){ pdf[0]=p2h; }
      f32x4 d0 = __builtin_amdgcn_mfma_f32_16x16x32_f16(w1f0, pdf, zero4, 0,0,0);
      f32x4 d1 = __builtin_amdgcn_mfma_f32_16x16x32_f16(w1f1, pdf, zero4, 0,0,0);
      half4v h0, l0, h1, l1;
      #pragma unroll
      for (int j=0;j<4;++j){
        float a = fmaxf(d0[j] + pv0[j] + qv0_c[j], 0.f);
        _Float16 hh = (_Float16)a;
        h0[j] = hh; l0[j] = (_Float16)(a - (float)hh);
        float b = fmaxf(d1[j] + pv1[j] + qv1_c[j], 0.f);
        _Float16 hb2 = (_Float16)b;
        h1[j] = hb2; l1[j] = (_Float16)(b - (float)hb2);
      }
      *(half4v*)&a1hi[c*136 + 16*t0 + 4*g] = h0;
      *(half4v*)&a1lo[c*136 + 16*t0 + 4*g] = l0;
      *(half4v*)&a1hi[c*136 + 16*t1 + 4*g] = h1;
      *(half4v*)&a1lo[c*136 + 16*t1 + 4*g] = l1;
      LGKM_BAR();
      // issue next tile's pos/Q gathers (hide under GEMM2)
      float qn0=0.f,qn1=0.f,qn2=0.f; f32x4 qv0_n=zero4, qv1_n=zero4;
      if (bn < ie){
        qn0=pos[sA_n*3+0]; qn1=pos[sA_n*3+1]; qn2=pos[sA_n*3+2];
        qv0_n = *(const f32x4*)(Q + (size_t)sA_n*HD + 16*t0 + 4*g);
        qv1_n = *(const f32x4*)(Q + (size_t)sA_n*HD + 16*t1 + 4*g);
      }
      f32x4 m0 = zero4, m1 = zero4;
      #pragma unroll
      for (int ks=0; ks<4; ++ks){
        half8 ah = *(const half8*)&a1hi[c*136 + ks*32 + g*8];
        half8 al = *(const half8*)&a1lo[c*136 + ks*32 + g*8];
        m0 = __builtin_amdgcn_mfma_f32_16x16x32_f16(ah, w2h[ks][0], m0, 0,0,0);
        m0 = __builtin_amdgcn_mfma_f32_16x16x32_f16(al, w2h[ks][0], m0, 0,0,0);
        m0 = __builtin_amdgcn_mfma_f32_16x16x32_f16(ah, w2l[ks][0], m0, 0,0,0);
        m1 = __builtin_amdgcn_mfma_f32_16x16x32_f16(ah, w2h[ks][1], m1, 0,0,0);
        m1 = __builtin_amdgcn_mfma_f32_16x16x32_f16(al, w2h[ks][1], m1, 0,0,0);
        m1 = __builtin_amdgcn_mfma_f32_16x16x32_f16(ah, w2l[ks][1], m1, 0,0,0);
      }
      if (nb == 16){
        acc0 += fmaxf(m0[0]+b2v0,0.f)+fmaxf(m0[1]+b2v0,0.f)+fmaxf(m0[2]+b2v0,0.f)+fmaxf(m0[3]+b2v0,0.f);
        acc1 += fmaxf(m1[0]+b2v1,0.f)+fmaxf(m1[1]+b2v1,0.f)+fmaxf(m1[2]+b2v1,0.f)+fmaxf(m1[3]+b2v1,0.f);
      } else {
        #pragma unroll
        for (int j=0;j<4;++j){
          if (4*g+j < nb){
            acc0 += fmaxf(m0[j]+b2v0, 0.f);
            acc1 += fmaxf(m1[j]+b2v1, 0.f);
          }
        }
      }
      LGKM_BAR();
      // rotate prefetch registers
      sA_c = sA_n; qc0=qn0; qc1=qn1; qc2=qn2; qv0_c=qv0_n; qv1_c=qv1_n;
    }
    acc0 += __shfl_xor(acc0, 16); acc0 += __shfl_xor(acc0, 32);
    acc1 += __shfl_xor(acc1, 16); acc1 += __shfl_xor(acc1, 32);
    if (g==0){
      float ic = invc[n];
      agg[n*HD + 16*t0 + c] = acc0*ic;
      agg[n*HD + 16*t1 + c] = acc1*ic;
    }
  }
}

// ---------------- update MLP via fp16-split MFMA ----------------

__global__ __launch_bounds__(512,1) void k_upd(
    float* __restrict__ hb, const float* __restrict__ mu, const float* __restrict__ rstd,
    const float* __restrict__ agg,
    const float* __restrict__ U1, const float* __restrict__ b1e,
    const float* __restrict__ U2, const float* __restrict__ bs2,
    float* __restrict__ sum, float* __restrict__ sumsq){
  __shared__ alignas(16) _Float16 Xhi[16*264];
  __shared__ alignas(16) _Float16 Xlo[16*264];
  __shared__ alignas(16) _Float16 Ahi[16*136];
  __shared__ alignas(16) _Float16 Alo[16*136];
  int tid = threadIdx.x;
  int n0 = blockIdx.x*16;
  {
    int node = tid>>5, chunk = tid&31;
    int n = n0 + node;
    int f = chunk*8;
    half8 xh, xl;
    if (f < 128){
      #pragma unroll
      for (int j=0;j<8;++j){
        float x = (hb[(size_t)n*HD + f+j] - mu[f+j]) * rstd[f+j];
        _Float16 h = (_Float16)x;
        xh[j] = h; xl[j] = (_Float16)(x - (float)h);
      }
    } else {
      #pragma unroll
      for (int j=0;j<8;++j){
        float x = agg[(size_t)n*HD + (f-128)+j];
        _Float16 h = (_Float16)x;
        xh[j] = h; xl[j] = (_Float16)(x - (float)h);
      }
    }
    *(half8*)&Xhi[node*264 + f] = xh;
    *(half8*)&Xlo[node*264 + f] = xl;
  }
  int wid = tid>>6, lane = tid&63, g = lane>>4, c = lane&15;
  int col = 16*wid + c;
  half8 b1h[8], b1l[8], b2h[4], b2l[4];
  #pragma unroll
  for (int ks=0; ks<8; ++ks){
    half8 fh, fl;
    #pragma unroll
    for (int j=0;j<8;++j){
      float w = U1[(size_t)(ks*32 + g*8 + j)*HD + col];
      _Float16 h = (_Float16)w;
      fh[j]=h; fl[j]=(_Float16)(w - (float)h);
    }
    b1h[ks]=fh; b1l[ks]=fl;
  }
  #pragma unroll
  for (int ks=0; ks<4; ++ks){
    half8 fh, fl;
    #pragma unroll
    for (int j=0;j<8;++j){
      float w = U2[(size_t)(ks*32 + g*8 + j)*HD + col];
      _Float16 h = (_Float16)w;
      fh[j]=h; fl[j]=(_Float16)(w - (float)h);
    }
    b2h[ks]=fh; b2l[ks]=fl;
  }
  f32x4 zero4 = {0.f,0.f,0.f,0.f};
  __syncthreads();
  f32x4 d = zero4;
  #pragma unroll
  for (int ks=0; ks<8; ++ks){
    half8 ah = *(const half8*)&Xhi[c*264 + ks*32 + g*8];
    half8 al = *(const half8*)&Xlo[c*264 + ks*32 + g*8];
    d = __builtin_amdgcn_mfma_f32_16x16x32_f16(ah, b1h[ks], d, 0,0,0);
    d = __builtin_amdgcn_mfma_f32_16x16x32_f16(al, b1h[ks], d, 0,0,0);
    d = __builtin_amdgcn_mfma_f32_16x16x32_f16(ah, b1l[ks], d, 0,0,0);
  }
  {
    float bb = b1e[col];
    #pragma unroll
    for (int jj=0;jj<4;++jj){
      float a = fmaxf(d[jj] + bb, 0.f);
      _Float16 h = (_Float16)a;
      Ahi[(g*4+jj)*136 + col] = h;
      Alo[(g*4+jj)*136 + col] = (_Float16)(a - (float)h);
    }
  }
  __syncthreads();
  f32x4 u = zero4;
  #pragma unroll
  for (int ks=0; ks<4; ++ks){
    half8 ah = *(const half8*)&Ahi[c*136 + ks*32 + g*8];
    half8 al = *(const half8*)&Alo[c*136 + ks*32 + g*8];
    u = __builtin_amdgcn_mfma_f32_16x16x32_f16(ah, b2h[ks], u, 0,0,0);
    u = __builtin_amdgcn_mfma_f32_16x16x32_f16(al, b2h[ks], u, 0,0,0);
    u = __builtin_amdgcn_mfma_f32_16x16x32_f16(ah, b2l[ks], u, 0,0,0);
  }
  float bc = bs2[col];
  float mc = mu[col], rc = rstd[col];
  float s=0.f, q=0.f;
  #pragma unroll
  for (int jj=0;jj<4;++jj){
    int n = n0 + g*4 + jj;
    float hn = (hb[(size_t)n*HD + col] - mc)*rc;
    float b0 = hn + fmaxf(u[jj] + bc, 0.f);
    hb[(size_t)n*HD + col] = b0;
    s += b0; q += b0*b0;
  }
  s += __shfl_xor(s,16); s += __shfl_xor(s,32);
  q += __shfl_xor(q,16); q += __shfl_xor(q,32);
  if (g==0){
    atomicAdd(&sum[col], s);
    atomicAdd(&sumsq[col], q);
  }
}

__global__ void k_normfin(const float* __restrict__ sum, const float* __restrict__ sumsq,
                          float* __restrict__ mu, float* __restrict__ rstd){
  int t=threadIdx.x;
  float m = sum[t]*(1.0f/NN);
  float var = sumsq[t]*(1.0f/NN) - m*m;
  mu[t]=m;
  rstd[t]=rsqrtf(fmaxf(var,0.0f)+EPSV);
}

// ---------------- decoder via fp16-split MFMA (k_upd template) ----------------

__global__ __launch_bounds__(512,1) void k_out(
    const float* __restrict__ hb, const float* __restrict__ mu, const float* __restrict__ rstd,
    const float* __restrict__ pos, const float* __restrict__ v,
    const float* __restrict__ W1, const float* __restrict__ b1,
    const float* __restrict__ W2, const float* __restrict__ b2,
    const float* __restrict__ domn, float* __restrict__ out){
  __shared__ alignas(16) _Float16 Xhi[16*136];
  __shared__ alignas(16) _Float16 Xlo[16*136];
  __shared__ alignas(16) _Float16 Ahi[16*136];
  __shared__ alignas(16) _Float16 Alo[16*136];
  int tid = threadIdx.x;
  int n0 = blockIdx.x*16;
  if (tid < 256){
    int node = tid>>4, chunk = tid&15;
    int n = n0 + node;
    int f = chunk*8;
    half8 xh, xl;
    #pragma unroll
    for (int j=0;j<8;++j){
      float x = (hb[(size_t)n*HD + f+j] - mu[f+j]) * rstd[f+j];
      _Float16 h = (_Float16)x;
      xh[j] = h; xl[j] = (_Float16)(x - (float)h);
    }
    *(half8*)&Xhi[node*136 + f] = xh;
    *(half8*)&Xlo[node*136 + f] = xl;
  }
  int wid = tid>>6, lane = tid&63, g = lane>>4, c = lane&15;
  int col = 16*wid + c;
  half8 bh[4], bl[4];
  #pragma unroll
  for (int ks=0; ks<4; ++ks){
    half8 fh, fl;
    #pragma unroll
    for (int j=0;j<8;++j){
      float w = W1[(size_t)(ks*32 + g*8 + j)*HD + col];
      _Float16 h = (_Float16)w;
      fh[j]=h; fl[j]=(_Float16)(w - (float)h);
    }
    bh[ks]=fh; bl[ks]=fl;
  }
  half8 w9h[4], w9l[4];
  if (wid==0){
    #pragma unroll
    for (int ks=0; ks<4; ++ks){
      half8 fh, fl;
      #pragma unroll
      for (int j=0;j<8;++j){
        float w = (c<9)? W2[(size_t)(ks*32 + g*8 + j)*9 + c] : 0.f;
        _Float16 h = (_Float16)w;
        fh[j]=h; fl[j]=(_Float16)(w - (float)h);
      }
      w9h[ks]=fh; w9l[ks]=fl;
    }
  }
  float b1c = b1[col];
  f32x4 zero4 = {0.f,0.f,0.f,0.f};
  __syncthreads();
  f32x4 d = zero4;
  #pragma unroll
  for (int ks=0; ks<4; ++ks){
    half8 ah = *(const half8*)&Xhi[c*136 + ks*32 + g*8];
    half8 al = *(const half8*)&Xlo[c*136 + ks*32 + g*8];
    d = __builtin_amdgcn_mfma_f32_16x16x32_f16(ah, bh[ks], d, 0,0,0);
    d = __builtin_amdgcn_mfma_f32_16x16x32_f16(al, bh[ks], d, 0,0,0);
    d = __builtin_amdgcn_mfma_f32_16x16x32_f16(ah, bl[ks], d, 0,0,0);
  }
  #pragma unroll
  for (int jj=0;jj<4;++jj){
    float a = fmaxf(d[jj] + b1c, 0.f);
    _Float16 h = (_Float16)a;
    Ahi[(g*4+jj)*136 + col] = h;
    Alo[(g*4+jj)*136 + col] = (_Float16)(a - (float)h);
  }
  __syncthreads();
  if (wid==0){
    f32x4 u = zero4;
    #pragma unroll
    for (int ks=0; ks<4; ++ks){
      half8 ah = *(const half8*)&Ahi[c*136 + ks*32 + g*8];
      half8 al = *(const half8*)&Alo[c*136 + ks*32 + g*8];
      u = __builtin_amdgcn_mfma_f32_16x16x32_f16(ah, w9h[ks], u, 0,0,0);
      u = __builtin_amdgcn_mfma_f32_16x16x32_f16(al, w9h[ks], u, 0,0,0);
      u = __builtin_amdgcn_mfma_f32_16x16x32_f16(ah, w9l[ks], u, 0,0,0);
    }
    if (c < 9){
      float bc = b2[c];
      #pragma unroll
      for (int jj=0;jj<4;++jj){
        int n = n0 + g*4 + jj;
        float p = u[jj] + bc;
        if (c < 3){
          p += pos[n*3+c];
          float dd = domn[c];
          p = p - floorf(p/dd)*dd;
          out[n*3+c] = p;
        } else {
          p += v[n*6 + (c-3)];
          out[3*NN + n*6 + (c-3)] = p;
        }
      }
    }
  }
}

__global__ void k_macro(const float* __restrict__ sum, const float* __restrict__ mu, const float* __restrict__ rstd,
                        const float* __restrict__ W1, const float* __restrict__ b1,
                        const float* __restrict__ W2, const float* __restrict__ b2,
                        float* __restrict__ out){
  __shared__ float hm[HD];
  __shared__ float as[HD];
  int t=threadIdx.x;
  hm[t] = (sum[t]*(1.0f/NN) - mu[t])*rstd[t];
  __syncthreads();
  float z=b1[t];
  for (int k=0;k<HD;++k) z += hm[k]*W1[k*HD+t];
  as[t]=relu_(z);
  __syncthreads();
  if (t<3){
    float p=b2[t];
    for (int k=0;k<HD;++k) p += as[k]*W2[k*3+t];
    out[9*NN+t]=p;
  }
}

// ---------------- host launch ----------------

extern "C" void kernel_launch(void* const* d_in, const int* in_sizes, int n_in,
                              void* d_out, int out_size, void* d_ws, size_t ws_size,
                              hipStream_t stream) {
  const float* v    = (const float*)d_in[0];
  const float* pos  = (const float*)d_in[1];
  const float* r    = (const float*)d_in[2];
  const float* dom  = (const float*)d_in[3];
  const float* tt   = (const float*)d_in[4];
  const float* xg   = (const float*)d_in[5];
  const float* domn = (const float*)d_in[6];
  const float* tn   = (const float*)d_in[7];
  const int*   eidx = (const int*)d_in[8];
  const float* embW1 = (const float*)d_in[10];
  const float* embB1 = (const float*)d_in[11];
  const float* embW2 = (const float*)d_in[12];
  const float* embB2 = (const float*)d_in[13];
  const float* msgW1 = (const float*)d_in[14];
  const float* msgB1 = (const float*)d_in[15];
  const float* msgW2 = (const float*)d_in[16];
  const float* msgB2 = (const float*)d_in[17];
  const float* updW1 = (const float*)d_in[18];
  const float* updB1 = (const float*)d_in[19];
  const float* updW2 = (const float*)d_in[20];
  const float* updB2 = (const float*)d_in[21];
  const float* outW1 = (const float*)d_in[22];
  const float* outB1 = (const float*)d_in[23];
  const float* outW2 = (const float*)d_in[24];
  const float* outB2 = (const float*)d_in[25];
  const float* macW1 = (const float*)d_in[26];
  const float* macB1 = (const float*)d_in[27];
  const float* macW2 = (const float*)d_in[28];
  const float* macB2 = (const float*)d_in[29];
  float* out = (float*)d_out;
  float* ws  = (float*)d_ws;

  float* hb    = ws;
  float* P     = ws + 1280000;
  float* Q     = ws + 2560000;
  float* agg   = ws + 3840000;
  float* invc  = ws + 5120000;
  float* b1eff = ws + 5130000;   // 13*128
  float* sum   = ws + 5131664;
  float* sumsq = ws + 5131792;
  float* mu    = ws + 5131920;
  float* rstd  = ws + 5132048;
  int* counts  = (int*)(ws + 5132304);
  int* offs    = counts + NN;       // NN+1
  int* cursor  = offs + NN + 1;
  int* csr     = cursor + NN;       // NE

  const int* srcA = eidx;
  const int* dstA = eidx + NE;

  hipMemsetAsync(counts, 0, NN*sizeof(int), stream);
  hipMemsetAsync(cursor, 0, NN*sizeof(int), stream);

  k_degree<<<(NE+255)/256, 256, 0, stream>>>(dstA, counts);
  k_scan<<<1, 1024, 0, stream>>>(counts, offs, invc);
  k_place<<<(NE+255)/256, 256, 0, stream>>>(srcA, dstA, offs, cursor, csr);
  k_biasfold<<<14, 128, 0, stream>>>(dom, tt, xg, domn, tn, embW1, embB1, msgW1, msgB1, updW1, updB1,
                                     b1eff, mu, rstd);
  k_embed<<<625, 512, 0, stream>>>(r, v, embW1, b1eff, embW2, embB2, hb);

  for (int l=0; l<NL; ++l){
    k_hW<<<625,512,0,stream>>>(hb, mu, rstd, v, r, msgW1 + (size_t)l*157*HD, b1eff + (1+l)*HD, P, Q);
    k_edge<<<5000,256,0,stream>>>(P, Q, pos, dom, offs, csr,
        msgW1 + ((size_t)l*157+142)*HD,
        msgW2 + (size_t)l*HD*HD, msgB2 + l*HD, invc, agg, sum, sumsq);
    k_upd<<<625,512,0,stream>>>(hb, mu, rstd, agg,
        updW1 + (size_t)l*268*HD, b1eff + (7+l)*HD,
        updW2 + (size_t)l*HD*HD, updB2 + l*HD, sum, sumsq);
    k_normfin<<<1,128,0,stream>>>(sum, sumsq, mu, rstd);
  }

  k_out<<<625,512,0,stream>>>(hb, mu, rstd, pos, v, outW1, outB1, outW2, outB2, domn, out);
  k_macro<<<1,128,0,stream>>>(sum, mu, rstd, macW1, macB1, macW2, macB2, out);
}